// Round 4
// baseline (180.274 us; speedup 1.0000x reference)
//
#include <hip/hip_runtime.h>
#include <hip/hip_bf16.h>

// ---------- common ----------
typedef __attribute__((ext_vector_type(8))) short short8;
typedef __attribute__((ext_vector_type(4))) float f32x4;
typedef __attribute__((ext_vector_type(4))) unsigned short ushort4v;

#define DI __device__ __forceinline__

DI unsigned short f2bf(float f) {
  union { float f; unsigned int u; } a; a.f = f;
  unsigned int u = a.u;
  return (unsigned short)((u + 0x7FFFu + ((u >> 16) & 1u)) >> 16);
}

// Problem constants
// B=8, H1=W1=56, N1=3136, C1=512, C2=256, NH=8, HD=64, WS=7, windows 8x8=64
// pooled Hp=Wp=56, Np=3136, M = B*3136 = 25088

// ---------- all f32 -> bf16 converts in one launch ----------
__global__ __launch_bounds__(256)
void cvt_all(const float* __restrict__ x, const float* __restrict__ Wq,
             const float* __restrict__ Wkv, const float* __restrict__ Wproj,
             const float* __restrict__ Wsr,
             unsigned short* __restrict__ xb, unsigned short* __restrict__ Wq_b,
             unsigned short* __restrict__ Wkv_b, unsigned short* __restrict__ Wproj_b,
             unsigned short* __restrict__ Wsr_b) {
  long i = (long)(blockIdx.x * 256 + threadIdx.x) * 4;
  const float* src; unsigned short* dst; long off;
  if (i < 12845056L)      { src = x;     dst = xb;      off = i; }
  else if (i < 13107200L) { src = Wq;    dst = Wq_b;    off = i - 12845056L; }
  else if (i < 13369344L) { src = Wkv;   dst = Wkv_b;   off = i - 13107200L; }
  else if (i < 13631488L) { src = Wproj; dst = Wproj_b; off = i - 13369344L; }
  else                    { src = Wsr;   dst = Wsr_b;   off = i - 13631488L; }
  float4 v = *(const float4*)&src[off];
  ushort4v o = { f2bf(v.x), f2bf(v.y), f2bf(v.z), f2bf(v.w) };
  *(ushort4v*)&dst[off] = o;
}

// ---------- 2x2 avgpool + convert: y (B,112*112,256) f32 -> pooled (B*3136,256) bf16 ----------
__global__ __launch_bounds__(256)
void pool_cvt(const float* __restrict__ y, unsigned short* __restrict__ out) {
  int t = blockIdx.x * 256 + threadIdx.x;      // 25088 * 64 threads
  int cv = (t & 63) * 4;
  int bp = t >> 6;
  int b = bp / 3136, p = bp % 3136;
  int hp = p / 56, wp = p % 56;
  const float* src = y + (((size_t)b * 12544) + hp * 224 + wp * 2) * 256 + cv;
  float4 a0 = *(const float4*)(src);
  float4 a1 = *(const float4*)(src + 256);
  float4 a2 = *(const float4*)(src + 28672);
  float4 a3 = *(const float4*)(src + 28672 + 256);
  float4 av;
  av.x = (a0.x + a1.x + a2.x + a3.x) * 0.25f;
  av.y = (a0.y + a1.y + a2.y + a3.y) * 0.25f;
  av.z = (a0.z + a1.z + a2.z + a3.z) * 0.25f;
  av.w = (a0.w + a1.w + a2.w + a3.w) * 0.25f;
  ushort4v o = { f2bf(av.x), f2bf(av.y), f2bf(av.z), f2bf(av.w) };
  *(ushort4v*)&out[(size_t)bp * 256 + cv] = o;
}

// ---------- fused: 1x1 conv GEMM (A = pooled bf16) -> +bias -> LayerNorm -> GELU -> bf16 ----------
// One block = 64 rows x full N=256, K=256. 4 waves, wave wv owns col-quadrant wv*64..+63.
__global__ __launch_bounds__(256)
void sr_gemm(const unsigned short* __restrict__ Ap, const unsigned short* __restrict__ Wsr_b,
             const float* __restrict__ bsr, const float* __restrict__ gn,
             const float* __restrict__ bn, unsigned short* __restrict__ out) {
  __shared__ unsigned short sA[64 * 64];
  __shared__ unsigned short sB[256 * 64];
  __shared__ float red[64 * 8];  // [row][wave*2 + {sum,sq}]

  const int tid = threadIdx.x;
  const int wv = tid >> 6;
  const int lane = tid & 63;
  const int lr = lane & 15;
  const int lk8 = (lane >> 4) * 8;
  const int lr4 = (lane >> 4) * 4;
  const int m0 = blockIdx.x * 64;
  const int cch = (lane & 7) * 8;

  f32x4 acc[4][4];
#pragma unroll
  for (int i = 0; i < 4; ++i)
#pragma unroll
    for (int j = 0; j < 4; ++j) acc[i][j] = (f32x4){0.f, 0.f, 0.f, 0.f};

  for (int kt = 0; kt < 256; kt += 64) {
    // A: 64 rows x 64 ch, wave wv stages rows wv*16..+15 (two 8-row chunks)
#pragma unroll
    for (int c = 0; c < 2; ++c) {
      __builtin_amdgcn_global_load_lds(
          (const __attribute__((address_space(1))) void*)
              (Ap + (size_t)(m0 + wv * 16 + c * 8 + (lane >> 3)) * 256 + cch + kt),
          (__attribute__((address_space(3))) void*)&sA[(wv * 16 + c * 8) * 64], 16, 0, 0);
    }
    // B: 256 rows x 64 ch, wave wv stages rows wv*64..+63
#pragma unroll
    for (int c = 0; c < 8; ++c) {
      __builtin_amdgcn_global_load_lds(
          (const __attribute__((address_space(1))) void*)
              (Wsr_b + (size_t)(wv * 64 + c * 8 + (lane >> 3)) * 256 + cch + kt),
          (__attribute__((address_space(3))) void*)&sB[(wv * 64 + c * 8) * 64], 16, 0, 0);
    }
    __syncthreads();
#pragma unroll
    for (int ks = 0; ks < 2; ++ks) {
      short8 af[4], bfr[4];
#pragma unroll
      for (int i = 0; i < 4; ++i)
        af[i] = *(const short8*)&sA[(i * 16 + lr) * 64 + ks * 32 + lk8];
#pragma unroll
      for (int j = 0; j < 4; ++j)
        bfr[j] = *(const short8*)&sB[(wv * 64 + j * 16 + lr) * 64 + ks * 32 + lk8];
#pragma unroll
      for (int i = 0; i < 4; ++i)
#pragma unroll
        for (int j = 0; j < 4; ++j)
          acc[i][j] = __builtin_amdgcn_mfma_f32_16x16x32_bf16(af[i], bfr[j], acc[i][j], 0, 0, 0);
    }
    __syncthreads();
  }

  // epilogue: +bias, LN(256) across the 4 waves, GELU, bf16 store
  float bsv[4], gnv[4], bnv[4];
#pragma unroll
  for (int j = 0; j < 4; ++j) {
    int col = wv * 64 + j * 16 + lr;
    bsv[j] = bsr[col]; gnv[j] = gn[col]; bnv[j] = bn[col];
  }
  float s_[4][4], q_[4][4];
#pragma unroll
  for (int i = 0; i < 4; ++i)
#pragma unroll
    for (int r = 0; r < 4; ++r) {
      float s = 0.f, q = 0.f;
#pragma unroll
      for (int j = 0; j < 4; ++j) {
        float v = acc[i][j][r] + bsv[j];
        acc[i][j][r] = v;
        s += v; q += v * v;
      }
      s_[i][r] = s; q_[i][r] = q;
    }
#pragma unroll
  for (int m = 1; m <= 8; m <<= 1)
#pragma unroll
    for (int i = 0; i < 4; ++i)
#pragma unroll
      for (int r = 0; r < 4; ++r) {
        s_[i][r] += __shfl_xor(s_[i][r], m);
        q_[i][r] += __shfl_xor(q_[i][r], m);
      }
  if (lr == 0) {
#pragma unroll
    for (int i = 0; i < 4; ++i)
#pragma unroll
      for (int r = 0; r < 4; ++r) {
        int row = i * 16 + lr4 + r;
        red[row * 8 + wv * 2 + 0] = s_[i][r];
        red[row * 8 + wv * 2 + 1] = q_[i][r];
      }
  }
  __syncthreads();
#pragma unroll
  for (int i = 0; i < 4; ++i) {
#pragma unroll
    for (int r = 0; r < 4; ++r) {
      int row = i * 16 + lr4 + r;
      float sum = red[row * 8 + 0] + red[row * 8 + 2] + red[row * 8 + 4] + red[row * 8 + 6];
      float sq  = red[row * 8 + 1] + red[row * 8 + 3] + red[row * 8 + 5] + red[row * 8 + 7];
      float mean = sum * (1.f / 256.f);
      float var = sq * (1.f / 256.f) - mean * mean;
      float rstd = rsqrtf(var + 1e-5f);
#pragma unroll
      for (int j = 0; j < 4; ++j) {
        float t = (acc[i][j][r] - mean) * rstd * gnv[j] + bnv[j];
        t = 0.5f * t * (1.f + erff(t * 0.70710678118654752f));
        out[(size_t)(m0 + row) * 256 + wv * 64 + j * 16 + lr] = f2bf(t);
      }
    }
  }
}

// ---------- 128x128 bf16 MFMA GEMM: out[m,n] = sum_k A[m,k]*Bw[n,k] ----------
// EPI 0: q windows (bf16)   EPI 2: kv windows (bf16, outp=k_win, out2=v_win)
// EPI 3: f32 + bias (final out)
template<int K, int N, int EPI>
__global__ __launch_bounds__(256, 2)
void gemm128(const unsigned short* __restrict__ A,
             const unsigned short* __restrict__ Bw,
             void* __restrict__ outp,
             const float* __restrict__ bias,
             unsigned short* __restrict__ out2) {
  __shared__ unsigned short sA[128 * 64];
  __shared__ unsigned short sB[128 * 64];
  const int tid = threadIdx.x;
  const int wv = tid >> 6;
  const int lane = tid & 63;
  const int m0 = blockIdx.y * 128;
  const int n0 = blockIdx.x * 128;
  const int wm = (wv >> 1) * 64;
  const int wn = (wv & 1) * 64;
  const int lr = lane & 15;
  const int lk8 = (lane >> 4) * 8;
  const int lr4 = (lane >> 4) * 4;

  f32x4 acc[4][4];
#pragma unroll
  for (int i = 0; i < 4; ++i)
#pragma unroll
    for (int j = 0; j < 4; ++j) acc[i][j] = (f32x4){0.f, 0.f, 0.f, 0.f};

  const int srow = wv * 32 + (lane >> 3);
  const int scol = (lane & 7) * 8;
  const unsigned short* gA = A + (size_t)(m0 + srow) * K + scol;
  const unsigned short* gB = Bw + (size_t)(n0 + srow) * K + scol;

  for (int kt = 0; kt < K; kt += 64) {
#pragma unroll
    for (int c = 0; c < 4; ++c) {
      __builtin_amdgcn_global_load_lds(
          (const __attribute__((address_space(1))) void*)(gA + (size_t)(c * 8) * K + kt),
          (__attribute__((address_space(3))) void*)&sA[(wv * 32 + c * 8) * 64], 16, 0, 0);
      __builtin_amdgcn_global_load_lds(
          (const __attribute__((address_space(1))) void*)(gB + (size_t)(c * 8) * K + kt),
          (__attribute__((address_space(3))) void*)&sB[(wv * 32 + c * 8) * 64], 16, 0, 0);
    }
    __syncthreads();
#pragma unroll
    for (int ks = 0; ks < 2; ++ks) {
      short8 af[4], bfr[4];
#pragma unroll
      for (int i = 0; i < 4; ++i)
        af[i] = *(const short8*)&sA[(wm + i * 16 + lr) * 64 + ks * 32 + lk8];
#pragma unroll
      for (int j = 0; j < 4; ++j)
        bfr[j] = *(const short8*)&sB[(wn + j * 16 + lr) * 64 + ks * 32 + lk8];
#pragma unroll
      for (int i = 0; i < 4; ++i)
#pragma unroll
        for (int j = 0; j < 4; ++j)
          acc[i][j] = __builtin_amdgcn_mfma_f32_16x16x32_bf16(af[i], bfr[j], acc[i][j], 0, 0, 0);
    }
    __syncthreads();
  }

#pragma unroll
  for (int i = 0; i < 4; ++i) {
#pragma unroll
    for (int j = 0; j < 4; ++j) {
#pragma unroll
      for (int r = 0; r < 4; ++r) {
        const int gm = m0 + wm + i * 16 + lr4 + r;
        const int gc = n0 + wn + j * 16 + lr;
        const float v = acc[i][j][r];
        if constexpr (EPI == 3) {
          ((float*)outp)[(size_t)gm * N + gc] = v + bias[gc];
        } else if constexpr (EPI == 0) {
          const int b = gm / 3136, pos = gm % 3136;
          const int h = pos / 56, ww = pos % 56;
          const int head = gc >> 6, d = gc & 63;
          const size_t idx = ((((size_t)(b * 8 + head)) * 64 + (h / 7) * 8 + (ww / 7)) * 49
                              + (h % 7) * 7 + (ww % 7)) * 64 + d;
          ((unsigned short*)outp)[idx] = f2bf(v);
        } else { // EPI == 2: kv scatter
          const int b = gm / 3136, pos = gm % 3136;
          const int h = pos / 56, ww = pos % 56;
          const int sel = gc >> 9, cc = gc & 511;
          const int head = cc >> 6, d = cc & 63;
          unsigned short* dst = sel ? out2 : (unsigned short*)outp;
          const size_t idx = ((((size_t)(b * 8 + head)) * 64 + (h / 7) * 8 + (ww / 7)) * 49
                              + (h % 7) * 7 + (ww % 7)) * 64 + d;
          dst[idx] = f2bf(v);
        }
      }
    }
  }
}

// ---------- windowed attention: one block per (b, head, window) ----------
__global__ __launch_bounds__(256)
void attn_win(const unsigned short* __restrict__ qw,
              const unsigned short* __restrict__ kw,
              const unsigned short* __restrict__ vw,
              unsigned short* __restrict__ aout) {
  __shared__ unsigned short q_s[64 * 64];
  __shared__ unsigned short k_s[64 * 64];
  __shared__ unsigned short vT_s[64 * 72];
  __shared__ unsigned short p_s[64 * 72];

  const int tid = threadIdx.x;
  const int bx = blockIdx.x;
  const int wv = tid >> 6;
  const int lane = tid & 63;
  const int lr = lane & 15;
  const int lk8 = (lane >> 4) * 8;
  const int lr4 = (lane >> 4) * 4;

  const size_t base = (size_t)bx * 3136;
  for (int i = tid * 8; i < 4096; i += 2048) {
    uint4 zv = make_uint4(0u, 0u, 0u, 0u);
    uint4 qv = zv, kvv = zv;
    if (i < 3136) {
      qv  = *(const uint4*)&qw[base + i];
      kvv = *(const uint4*)&kw[base + i];
    }
    *(uint4*)&q_s[i] = qv;
    *(uint4*)&k_s[i] = kvv;
  }
  for (int i = tid * 8; i < 4096; i += 2048) {
    int j = i >> 6, d0 = i & 63;
    union { uint4 v; unsigned short u[8]; } t;
    t.v = make_uint4(0u, 0u, 0u, 0u);
    if (i < 3136) t.v = *(const uint4*)&vw[base + i];
#pragma unroll
    for (int e = 0; e < 8; ++e) vT_s[(d0 + e) * 72 + j] = t.u[e];
  }
  __syncthreads();

  f32x4 s[4];
#pragma unroll
  for (int j = 0; j < 4; ++j) s[j] = (f32x4){0.f, 0.f, 0.f, 0.f};
#pragma unroll
  for (int ks = 0; ks < 2; ++ks) {
    short8 aq = *(const short8*)&q_s[(wv * 16 + lr) * 64 + ks * 32 + lk8];
#pragma unroll
    for (int j = 0; j < 4; ++j) {
      short8 bk = *(const short8*)&k_s[(j * 16 + lr) * 64 + ks * 32 + lk8];
      s[j] = __builtin_amdgcn_mfma_f32_16x16x32_bf16(aq, bk, s[j], 0, 0, 0);
    }
  }
#pragma unroll
  for (int j = 0; j < 4; ++j) {
    if (j * 16 + lr >= 49) {
#pragma unroll
      for (int r = 0; r < 4; ++r) s[j][r] = -1e30f;
    }
  }
  float mx[4], sm[4];
#pragma unroll
  for (int r = 0; r < 4; ++r)
    mx[r] = fmaxf(fmaxf(s[0][r], s[1][r]), fmaxf(s[2][r], s[3][r]));
#pragma unroll
  for (int m = 1; m <= 8; m <<= 1)
#pragma unroll
    for (int r = 0; r < 4; ++r) mx[r] = fmaxf(mx[r], __shfl_xor(mx[r], m));
  const float cexp = 0.125f * 1.4426950408889634f;
  float pv[4][4];
#pragma unroll
  for (int j = 0; j < 4; ++j)
#pragma unroll
    for (int r = 0; r < 4; ++r)
      pv[j][r] = exp2f((s[j][r] - mx[r]) * cexp);
#pragma unroll
  for (int r = 0; r < 4; ++r)
    sm[r] = pv[0][r] + pv[1][r] + pv[2][r] + pv[3][r];
#pragma unroll
  for (int m = 1; m <= 8; m <<= 1)
#pragma unroll
    for (int r = 0; r < 4; ++r) sm[r] += __shfl_xor(sm[r], m);
#pragma unroll
  for (int r = 0; r < 4; ++r) sm[r] = 1.f / sm[r];
#pragma unroll
  for (int j = 0; j < 4; ++j)
#pragma unroll
    for (int r = 0; r < 4; ++r)
      p_s[(wv * 16 + lr4 + r) * 72 + j * 16 + lr] = f2bf(pv[j][r] * sm[r]);
  __syncthreads();

  f32x4 o[4];
#pragma unroll
  for (int dt = 0; dt < 4; ++dt) o[dt] = (f32x4){0.f, 0.f, 0.f, 0.f};
#pragma unroll
  for (int ks = 0; ks < 2; ++ks) {
    short8 pa = *(const short8*)&p_s[(wv * 16 + lr) * 72 + ks * 32 + lk8];
#pragma unroll
    for (int dt = 0; dt < 4; ++dt) {
      short8 vb = *(const short8*)&vT_s[(dt * 16 + lr) * 72 + ks * 32 + lk8];
      o[dt] = __builtin_amdgcn_mfma_f32_16x16x32_bf16(pa, vb, o[dt], 0, 0, 0);
    }
  }
  const int b = bx >> 9;
  const int head = (bx >> 6) & 7;
  const int win = bx & 63;
  const int ht = win >> 3, wt = win & 7;
#pragma unroll
  for (int r = 0; r < 4; ++r) {
    int prow = wv * 16 + lr4 + r;
    if (prow < 49) {
      int wr = prow / 7, wc = prow % 7;
      size_t gm = (size_t)b * 3136 + (ht * 7 + wr) * 56 + wt * 7 + wc;
#pragma unroll
      for (int dt = 0; dt < 4; ++dt)
        aout[gm * 512 + head * 64 + dt * 16 + lr] = f2bf(o[dt][r]);
    }
  }
}

// ---------- launcher ----------
extern "C" void kernel_launch(void* const* d_in, const int* in_sizes, int n_in,
                              void* d_out, int out_size, void* d_ws, size_t ws_size,
                              hipStream_t stream) {
  const float* x     = (const float*)d_in[0];
  const float* y     = (const float*)d_in[1];
  const float* Wq    = (const float*)d_in[2];
  const float* Wkv   = (const float*)d_in[3];
  const float* Wproj = (const float*)d_in[4];
  const float* bproj = (const float*)d_in[5];
  const float* Wsr   = (const float*)d_in[6];
  const float* bsr   = (const float*)d_in[7];
  const float* gn    = (const float*)d_in[8];
  const float* bn    = (const float*)d_in[9];
  float* out = (float*)d_out;

  // Workspace (bytes). regA is reused three times:
  //   xb (gemmQ input) -> pooled bf16 (sr_gemm input) -> attn output
  char* ws = (char*)d_ws;
  unsigned short* Wq_b    = (unsigned short*)ws; ws += 524288;
  unsigned short* Wkv_b   = (unsigned short*)ws; ws += 524288;
  unsigned short* Wproj_b = (unsigned short*)ws; ws += 524288;
  unsigned short* Wsr_b   = (unsigned short*)ws; ws += 131072;
  unsigned short* regA    = (unsigned short*)ws; ws += 25690112;
  unsigned short* q_win   = (unsigned short*)ws; ws += 25690112;
  unsigned short* regC    = (unsigned short*)ws; ws += 12845056; // y2 bf16 (25088x256)
  unsigned short* k_win   = (unsigned short*)ws; ws += 25690112;
  unsigned short* v_win   = (unsigned short*)ws; ws += 25690112;

  // all converts in one launch (x -> regA)
  cvt_all<<<13376, 256, 0, stream>>>(x, Wq, Wkv, Wproj, Wsr,
                                     regA, Wq_b, Wkv_b, Wproj_b, Wsr_b);

  // q projection -> window layout (consumes regA as xb)
  gemm128<512, 512, 0><<<dim3(4, 196), 256, 0, stream>>>(regA, Wq_b, q_win, nullptr, nullptr);

  // KV preprocess: pool (streaming, full grid) then fused conv+bias+LN+GELU GEMM
  pool_cvt<<<6272, 256, 0, stream>>>(y, regA);   // regA reused: pooled bf16
  sr_gemm<<<392, 256, 0, stream>>>(regA, Wsr_b, bsr, gn, bn, regC);

  // kv projection -> window layouts
  gemm128<256, 1024, 2><<<dim3(8, 196), 256, 0, stream>>>(regC, Wkv_b, k_win, nullptr, v_win);

  // windowed attention -> natural layout bf16 (reuses regA)
  attn_win<<<4096, 256, 0, stream>>>(q_win, k_win, v_win, regA);

  // output projection + bias -> f32 d_out
  gemm128<512, 512, 3><<<dim3(4, 196), 256, 0, stream>>>(regA, Wproj_b, out, bproj, nullptr);
}

// Round 5
// 174.286 us; speedup vs baseline: 1.0344x; 1.0344x over previous
//
#include <hip/hip_runtime.h>
#include <hip/hip_bf16.h>

// ---------- common ----------
typedef __attribute__((ext_vector_type(8))) short short8;
typedef __attribute__((ext_vector_type(4))) float f32x4;
typedef __attribute__((ext_vector_type(4))) unsigned short ushort4v;

#define DI __device__ __forceinline__

DI unsigned short f2bf(float f) {
  union { float f; unsigned int u; } a; a.f = f;
  unsigned int u = a.u;
  return (unsigned short)((u + 0x7FFFu + ((u >> 16) & 1u)) >> 16);
}

#define BARRIER() do { asm volatile("" ::: "memory"); __builtin_amdgcn_s_barrier(); asm volatile("" ::: "memory"); } while (0)

// Problem constants: B=8, H1=W1=56, N1=3136, C1=512, C2=256, NH=8, HD=64, WS=7
// pooled Hp=Wp=56, M = B*3136 = 25088

// ---------- all f32 -> bf16 converts in one launch ----------
__global__ __launch_bounds__(256)
void cvt_all(const float* __restrict__ x, const float* __restrict__ Wq,
             const float* __restrict__ Wkv, const float* __restrict__ Wproj,
             const float* __restrict__ Wsr,
             unsigned short* __restrict__ xb, unsigned short* __restrict__ Wq_b,
             unsigned short* __restrict__ Wkv_b, unsigned short* __restrict__ Wproj_b,
             unsigned short* __restrict__ Wsr_b) {
  long i = (long)(blockIdx.x * 256 + threadIdx.x) * 4;
  const float* src; unsigned short* dst; long off;
  if (i < 12845056L)      { src = x;     dst = xb;      off = i; }
  else if (i < 13107200L) { src = Wq;    dst = Wq_b;    off = i - 12845056L; }
  else if (i < 13369344L) { src = Wkv;   dst = Wkv_b;   off = i - 13107200L; }
  else if (i < 13631488L) { src = Wproj; dst = Wproj_b; off = i - 13369344L; }
  else                    { src = Wsr;   dst = Wsr_b;   off = i - 13631488L; }
  float4 v = *(const float4*)&src[off];
  ushort4v o = { f2bf(v.x), f2bf(v.y), f2bf(v.z), f2bf(v.w) };
  *(ushort4v*)&dst[off] = o;
}

// ---------- 2x2 avgpool + convert ----------
__global__ __launch_bounds__(256)
void pool_cvt(const float* __restrict__ y, unsigned short* __restrict__ out) {
  int t = blockIdx.x * 256 + threadIdx.x;
  int cv = (t & 63) * 4;
  int bp = t >> 6;
  int b = bp / 3136, p = bp % 3136;
  int hp = p / 56, wp = p % 56;
  const float* src = y + (((size_t)b * 12544) + hp * 224 + wp * 2) * 256 + cv;
  float4 a0 = *(const float4*)(src);
  float4 a1 = *(const float4*)(src + 256);
  float4 a2 = *(const float4*)(src + 28672);
  float4 a3 = *(const float4*)(src + 28672 + 256);
  float4 av;
  av.x = (a0.x + a1.x + a2.x + a3.x) * 0.25f;
  av.y = (a0.y + a1.y + a2.y + a3.y) * 0.25f;
  av.z = (a0.z + a1.z + a2.z + a3.z) * 0.25f;
  av.w = (a0.w + a1.w + a2.w + a3.w) * 0.25f;
  ushort4v o = { f2bf(av.x), f2bf(av.y), f2bf(av.z), f2bf(av.w) };
  *(ushort4v*)&out[(size_t)bp * 256 + cv] = o;
}

// ---------- fused: 1x1 conv GEMM -> +bias -> LayerNorm -> GELU -> bf16 ----------
__global__ __launch_bounds__(256)
void sr_gemm(const unsigned short* __restrict__ Ap, const unsigned short* __restrict__ Wsr_b,
             const float* __restrict__ bsr, const float* __restrict__ gn,
             const float* __restrict__ bn, unsigned short* __restrict__ out) {
  __shared__ unsigned short sA[64 * 64];
  __shared__ unsigned short sB[256 * 64];
  __shared__ float red[64 * 8];

  const int tid = threadIdx.x;
  const int wv = tid >> 6;
  const int lane = tid & 63;
  const int lr = lane & 15;
  const int lk8 = (lane >> 4) * 8;
  const int lr4 = (lane >> 4) * 4;
  const int m0 = blockIdx.x * 64;
  const int cch = (lane & 7) * 8;

  f32x4 acc[4][4];
#pragma unroll
  for (int i = 0; i < 4; ++i)
#pragma unroll
    for (int j = 0; j < 4; ++j) acc[i][j] = (f32x4){0.f, 0.f, 0.f, 0.f};

  for (int kt = 0; kt < 256; kt += 64) {
#pragma unroll
    for (int c = 0; c < 2; ++c) {
      __builtin_amdgcn_global_load_lds(
          (const __attribute__((address_space(1))) void*)
              (Ap + (size_t)(m0 + wv * 16 + c * 8 + (lane >> 3)) * 256 + cch + kt),
          (__attribute__((address_space(3))) void*)&sA[(wv * 16 + c * 8) * 64], 16, 0, 0);
    }
#pragma unroll
    for (int c = 0; c < 8; ++c) {
      __builtin_amdgcn_global_load_lds(
          (const __attribute__((address_space(1))) void*)
              (Wsr_b + (size_t)(wv * 64 + c * 8 + (lane >> 3)) * 256 + cch + kt),
          (__attribute__((address_space(3))) void*)&sB[(wv * 64 + c * 8) * 64], 16, 0, 0);
    }
    __syncthreads();
#pragma unroll
    for (int ks = 0; ks < 2; ++ks) {
      short8 af[4], bfr[4];
#pragma unroll
      for (int i = 0; i < 4; ++i)
        af[i] = *(const short8*)&sA[(i * 16 + lr) * 64 + ks * 32 + lk8];
#pragma unroll
      for (int j = 0; j < 4; ++j)
        bfr[j] = *(const short8*)&sB[(wv * 64 + j * 16 + lr) * 64 + ks * 32 + lk8];
#pragma unroll
      for (int i = 0; i < 4; ++i)
#pragma unroll
        for (int j = 0; j < 4; ++j)
          acc[i][j] = __builtin_amdgcn_mfma_f32_16x16x32_bf16(af[i], bfr[j], acc[i][j], 0, 0, 0);
    }
    __syncthreads();
  }

  float bsv[4], gnv[4], bnv[4];
#pragma unroll
  for (int j = 0; j < 4; ++j) {
    int col = wv * 64 + j * 16 + lr;
    bsv[j] = bsr[col]; gnv[j] = gn[col]; bnv[j] = bn[col];
  }
  float s_[4][4], q_[4][4];
#pragma unroll
  for (int i = 0; i < 4; ++i)
#pragma unroll
    for (int r = 0; r < 4; ++r) {
      float s = 0.f, q = 0.f;
#pragma unroll
      for (int j = 0; j < 4; ++j) {
        float v = acc[i][j][r] + bsv[j];
        acc[i][j][r] = v;
        s += v; q += v * v;
      }
      s_[i][r] = s; q_[i][r] = q;
    }
#pragma unroll
  for (int m = 1; m <= 8; m <<= 1)
#pragma unroll
    for (int i = 0; i < 4; ++i)
#pragma unroll
      for (int r = 0; r < 4; ++r) {
        s_[i][r] += __shfl_xor(s_[i][r], m);
        q_[i][r] += __shfl_xor(q_[i][r], m);
      }
  if (lr == 0) {
#pragma unroll
    for (int i = 0; i < 4; ++i)
#pragma unroll
      for (int r = 0; r < 4; ++r) {
        int row = i * 16 + lr4 + r;
        red[row * 8 + wv * 2 + 0] = s_[i][r];
        red[row * 8 + wv * 2 + 1] = q_[i][r];
      }
  }
  __syncthreads();
#pragma unroll
  for (int i = 0; i < 4; ++i) {
#pragma unroll
    for (int r = 0; r < 4; ++r) {
      int row = i * 16 + lr4 + r;
      float sum = red[row * 8 + 0] + red[row * 8 + 2] + red[row * 8 + 4] + red[row * 8 + 6];
      float sq  = red[row * 8 + 1] + red[row * 8 + 3] + red[row * 8 + 5] + red[row * 8 + 7];
      float mean = sum * (1.f / 256.f);
      float var = sq * (1.f / 256.f) - mean * mean;
      float rstd = rsqrtf(var + 1e-5f);
#pragma unroll
      for (int j = 0; j < 4; ++j) {
        float t = (acc[i][j][r] - mean) * rstd * gnv[j] + bnv[j];
        t = 0.5f * t * (1.f + erff(t * 0.70710678118654752f));
        out[(size_t)(m0 + row) * 256 + wv * 64 + j * 16 + lr] = f2bf(t);
      }
    }
  }
}

// ---------- 256x256 8-wave pipelined GEMM (4-phase/K-tile, counted vmcnt, swizzled LDS) ----------
// out[m,n] = sum_k A[m,k]*Bw[n,k].  EPI 0: q windows; EPI 2: kv windows; EPI 3: f32+bias.
template<int K, int N, int EPI>
__global__ __launch_bounds__(512, 2)
void gemm256(const unsigned short* __restrict__ A,
             const unsigned short* __restrict__ Bw,
             void* __restrict__ outp,
             const float* __restrict__ bias,
             unsigned short* __restrict__ out2) {
  // LDS: 2 slots x (A 256x64 | B 256x64) bf16, linear layout, content swizzled via source.
  __shared__ unsigned short lds[65536];  // 128 KiB
  const int tid = threadIdx.x;
  const int wv = tid >> 6;        // 0..7
  const int lane = tid & 63;
  const int wm = wv >> 2;         // 0..1 (M half)
  const int wn = wv & 3;          // 0..3 (N quarter)
  const int m0 = blockIdx.y * 256;
  const int n0 = blockIdx.x * 256;
  const int lr = lane & 15;
  const int lg = lane >> 4;       // 0..3
  const int lr4 = lg * 4;
  const int srow8 = lane >> 3;    // 0..7
  const int sl8 = lane & 7;

  f32x4 acc[8][4];
#pragma unroll
  for (int i = 0; i < 8; ++i)
#pragma unroll
    for (int j = 0; j < 4; ++j) acc[i][j] = (f32x4){0.f, 0.f, 0.f, 0.f};

  // Stage round rr (64 rows) of tile t1 into slot t1&1. Source column XOR-swizzled by row;
  // LDS dest stays linear (wave-uniform base + lane*16B).
  auto stageA = [&](int t1, int rr) {
    int trow = rr * 64 + wv * 8 + srow8;
    int sx = sl8 ^ (trow & 7);
    __builtin_amdgcn_global_load_lds(
        (const __attribute__((address_space(1))) void*)(A + (size_t)(m0 + trow) * K + t1 * 64 + sx * 8),
        (__attribute__((address_space(3))) void*)&lds[(t1 & 1) * 32768 + (rr * 64 + wv * 8) * 64],
        16, 0, 0);
  };
  auto stageB = [&](int t1, int rr) {
    int trow = rr * 64 + wv * 8 + srow8;
    int sx = sl8 ^ (trow & 7);
    __builtin_amdgcn_global_load_lds(
        (const __attribute__((address_space(1))) void*)(Bw + (size_t)(n0 + trow) * K + t1 * 64 + sx * 8),
        (__attribute__((address_space(3))) void*)&lds[(t1 & 1) * 32768 + 16384 + (rr * 64 + wv * 8) * 64],
        16, 0, 0);
  };
  // Swizzled fragment reads (slot ^ row&7 inverts the source swizzle).
  auto rdA = [&](int s, int mf, int ks) -> short8 {
    int row = wm * 128 + mf * 16 + lr;
    int slot = ((ks << 2) + lg) ^ (row & 7);
    return *(const short8*)&lds[s * 32768 + row * 64 + slot * 8];
  };
  auto rdB = [&](int s, int nf, int ks) -> short8 {
    int row = wn * 64 + nf * 16 + lr;
    int slot = ((ks << 2) + lg) ^ (row & 7);
    return *(const short8*)&lds[s * 32768 + 16384 + row * 64 + slot * 8];
  };

  // Prologue: full tile 0, A1/A3 issued last. vmcnt(2) leaves exactly {A1,A3} in flight.
  stageA(0, 0); stageA(0, 2);
  stageB(0, 0); stageB(0, 1); stageB(0, 2); stageB(0, 3);
  stageA(0, 1); stageA(0, 3);
  asm volatile("s_waitcnt vmcnt(2)" ::: "memory");
  BARRIER();

  const int NT = K / 64;
  for (int t = 0; t < NT; ++t) {
    const int s = t & 1;
    short8 bfr[4][2];
    // ---- phase 0: B frags + A frags m0,m1 ----
    stageA(t + 1, 0); stageA(t + 1, 2);
#pragma unroll
    for (int j = 0; j < 4; ++j) { bfr[j][0] = rdB(s, j, 0); bfr[j][1] = rdB(s, j, 1); }
    {
      short8 x0 = rdA(s, 0, 0), x1 = rdA(s, 0, 1);
      short8 y0 = rdA(s, 1, 0), y1 = rdA(s, 1, 1);
      BARRIER();
      __builtin_amdgcn_s_setprio(1);
#pragma unroll
      for (int j = 0; j < 4; ++j) {
        acc[0][j] = __builtin_amdgcn_mfma_f32_16x16x32_bf16(x0, bfr[j][0], acc[0][j], 0, 0, 0);
        acc[0][j] = __builtin_amdgcn_mfma_f32_16x16x32_bf16(x1, bfr[j][1], acc[0][j], 0, 0, 0);
        acc[1][j] = __builtin_amdgcn_mfma_f32_16x16x32_bf16(y0, bfr[j][0], acc[1][j], 0, 0, 0);
        acc[1][j] = __builtin_amdgcn_mfma_f32_16x16x32_bf16(y1, bfr[j][1], acc[1][j], 0, 0, 0);
      }
      __builtin_amdgcn_s_setprio(0);
      BARRIER();
    }
    // ---- phase 1: A frags m2,m3; retire old A1/A3 before waves touch rows 64-127 ----
    stageB(t + 1, 0); stageB(t + 1, 1);
    {
      short8 x0 = rdA(s, 2, 0), x1 = rdA(s, 2, 1);
      short8 y0 = rdA(s, 3, 0), y1 = rdA(s, 3, 1);
      BARRIER();
      __builtin_amdgcn_s_setprio(1);
#pragma unroll
      for (int j = 0; j < 4; ++j) {
        acc[2][j] = __builtin_amdgcn_mfma_f32_16x16x32_bf16(x0, bfr[j][0], acc[2][j], 0, 0, 0);
        acc[2][j] = __builtin_amdgcn_mfma_f32_16x16x32_bf16(x1, bfr[j][1], acc[2][j], 0, 0, 0);
        acc[3][j] = __builtin_amdgcn_mfma_f32_16x16x32_bf16(y0, bfr[j][0], acc[3][j], 0, 0, 0);
        acc[3][j] = __builtin_amdgcn_mfma_f32_16x16x32_bf16(y1, bfr[j][1], acc[3][j], 0, 0, 0);
      }
      __builtin_amdgcn_s_setprio(0);
      asm volatile("s_waitcnt vmcnt(4)" ::: "memory");  // retires A1(t),A3(t)
      BARRIER();
    }
    // ---- phase 2: A frags m4,m5 ----
    stageB(t + 1, 2); stageB(t + 1, 3);
    {
      short8 x0 = rdA(s, 4, 0), x1 = rdA(s, 4, 1);
      short8 y0 = rdA(s, 5, 0), y1 = rdA(s, 5, 1);
      BARRIER();
      __builtin_amdgcn_s_setprio(1);
#pragma unroll
      for (int j = 0; j < 4; ++j) {
        acc[4][j] = __builtin_amdgcn_mfma_f32_16x16x32_bf16(x0, bfr[j][0], acc[4][j], 0, 0, 0);
        acc[4][j] = __builtin_amdgcn_mfma_f32_16x16x32_bf16(x1, bfr[j][1], acc[4][j], 0, 0, 0);
        acc[5][j] = __builtin_amdgcn_mfma_f32_16x16x32_bf16(y0, bfr[j][0], acc[5][j], 0, 0, 0);
        acc[5][j] = __builtin_amdgcn_mfma_f32_16x16x32_bf16(y1, bfr[j][1], acc[5][j], 0, 0, 0);
      }
      __builtin_amdgcn_s_setprio(0);
      BARRIER();
    }
    // ---- phase 3: A frags m6,m7; boundary vmcnt(2) leaves {A1,A3}(t+1) in flight ----
    stageA(t + 1, 1); stageA(t + 1, 3);
    {
      short8 x0 = rdA(s, 6, 0), x1 = rdA(s, 6, 1);
      short8 y0 = rdA(s, 7, 0), y1 = rdA(s, 7, 1);
      BARRIER();
      __builtin_amdgcn_s_setprio(1);
#pragma unroll
      for (int j = 0; j < 4; ++j) {
        acc[6][j] = __builtin_amdgcn_mfma_f32_16x16x32_bf16(x0, bfr[j][0], acc[6][j], 0, 0, 0);
        acc[6][j] = __builtin_amdgcn_mfma_f32_16x16x32_bf16(x1, bfr[j][1], acc[6][j], 0, 0, 0);
        acc[7][j] = __builtin_amdgcn_mfma_f32_16x16x32_bf16(y0, bfr[j][0], acc[7][j], 0, 0, 0);
        acc[7][j] = __builtin_amdgcn_mfma_f32_16x16x32_bf16(y1, bfr[j][1], acc[7][j], 0, 0, 0);
      }
      __builtin_amdgcn_s_setprio(0);
      asm volatile("s_waitcnt vmcnt(2)" ::: "memory");  // tile t+1 (minus its A1/A3) landed
      BARRIER();
    }
  }

  // ---- epilogue ----
#pragma unroll
  for (int i = 0; i < 8; ++i) {
#pragma unroll
    for (int j = 0; j < 4; ++j) {
#pragma unroll
      for (int r = 0; r < 4; ++r) {
        const int gm = m0 + wm * 128 + i * 16 + lr4 + r;
        const int gc = n0 + wn * 64 + j * 16 + lr;
        const float v = acc[i][j][r];
        if constexpr (EPI == 3) {
          ((float*)outp)[(size_t)gm * N + gc] = v + bias[gc];
        } else if constexpr (EPI == 0) {
          const int b = gm / 3136, pos = gm % 3136;
          const int h = pos / 56, ww = pos % 56;
          const int head = gc >> 6, d = gc & 63;
          const size_t idx = ((((size_t)(b * 8 + head)) * 64 + (h / 7) * 8 + (ww / 7)) * 49
                              + (h % 7) * 7 + (ww % 7)) * 64 + d;
          ((unsigned short*)outp)[idx] = f2bf(v);
        } else { // EPI == 2
          const int b = gm / 3136, pos = gm % 3136;
          const int h = pos / 56, ww = pos % 56;
          const int sel = gc >> 9, cc = gc & 511;
          const int head = cc >> 6, d = cc & 63;
          unsigned short* dst = sel ? out2 : (unsigned short*)outp;
          const size_t idx = ((((size_t)(b * 8 + head)) * 64 + (h / 7) * 8 + (ww / 7)) * 49
                              + (h % 7) * 7 + (ww % 7)) * 64 + d;
          dst[idx] = f2bf(v);
        }
      }
    }
  }
}

// ---------- windowed attention ----------
__global__ __launch_bounds__(256)
void attn_win(const unsigned short* __restrict__ qw,
              const unsigned short* __restrict__ kw,
              const unsigned short* __restrict__ vw,
              unsigned short* __restrict__ aout) {
  __shared__ unsigned short q_s[64 * 64];
  __shared__ unsigned short k_s[64 * 64];
  __shared__ unsigned short vT_s[64 * 72];
  __shared__ unsigned short p_s[64 * 72];

  const int tid = threadIdx.x;
  const int bx = blockIdx.x;
  const int wv = tid >> 6;
  const int lane = tid & 63;
  const int lr = lane & 15;
  const int lk8 = (lane >> 4) * 8;
  const int lr4 = (lane >> 4) * 4;

  const size_t base = (size_t)bx * 3136;
  for (int i = tid * 8; i < 4096; i += 2048) {
    uint4 zv = make_uint4(0u, 0u, 0u, 0u);
    uint4 qv = zv, kvv = zv;
    if (i < 3136) {
      qv  = *(const uint4*)&qw[base + i];
      kvv = *(const uint4*)&kw[base + i];
    }
    *(uint4*)&q_s[i] = qv;
    *(uint4*)&k_s[i] = kvv;
  }
  for (int i = tid * 8; i < 4096; i += 2048) {
    int j = i >> 6, d0 = i & 63;
    union { uint4 v; unsigned short u[8]; } t;
    t.v = make_uint4(0u, 0u, 0u, 0u);
    if (i < 3136) t.v = *(const uint4*)&vw[base + i];
#pragma unroll
    for (int e = 0; e < 8; ++e) vT_s[(d0 + e) * 72 + j] = t.u[e];
  }
  __syncthreads();

  f32x4 s[4];
#pragma unroll
  for (int j = 0; j < 4; ++j) s[j] = (f32x4){0.f, 0.f, 0.f, 0.f};
#pragma unroll
  for (int ks = 0; ks < 2; ++ks) {
    short8 aq = *(const short8*)&q_s[(wv * 16 + lr) * 64 + ks * 32 + lk8];
#pragma unroll
    for (int j = 0; j < 4; ++j) {
      short8 bk = *(const short8*)&k_s[(j * 16 + lr) * 64 + ks * 32 + lk8];
      s[j] = __builtin_amdgcn_mfma_f32_16x16x32_bf16(aq, bk, s[j], 0, 0, 0);
    }
  }
#pragma unroll
  for (int j = 0; j < 4; ++j) {
    if (j * 16 + lr >= 49) {
#pragma unroll
      for (int r = 0; r < 4; ++r) s[j][r] = -1e30f;
    }
  }
  float mx[4], sm[4];
#pragma unroll
  for (int r = 0; r < 4; ++r)
    mx[r] = fmaxf(fmaxf(s[0][r], s[1][r]), fmaxf(s[2][r], s[3][r]));
#pragma unroll
  for (int m = 1; m <= 8; m <<= 1)
#pragma unroll
    for (int r = 0; r < 4; ++r) mx[r] = fmaxf(mx[r], __shfl_xor(mx[r], m));
  const float cexp = 0.125f * 1.4426950408889634f;
  float pv[4][4];
#pragma unroll
  for (int j = 0; j < 4; ++j)
#pragma unroll
    for (int r = 0; r < 4; ++r)
      pv[j][r] = exp2f((s[j][r] - mx[r]) * cexp);
#pragma unroll
  for (int r = 0; r < 4; ++r)
    sm[r] = pv[0][r] + pv[1][r] + pv[2][r] + pv[3][r];
#pragma unroll
  for (int m = 1; m <= 8; m <<= 1)
#pragma unroll
    for (int r = 0; r < 4; ++r) sm[r] += __shfl_xor(sm[r], m);
#pragma unroll
  for (int r = 0; r < 4; ++r) sm[r] = 1.f / sm[r];
#pragma unroll
  for (int j = 0; j < 4; ++j)
#pragma unroll
    for (int r = 0; r < 4; ++r)
      p_s[(wv * 16 + lr4 + r) * 72 + j * 16 + lr] = f2bf(pv[j][r] * sm[r]);
  __syncthreads();

  f32x4 o[4];
#pragma unroll
  for (int dt = 0; dt < 4; ++dt) o[dt] = (f32x4){0.f, 0.f, 0.f, 0.f};
#pragma unroll
  for (int ks = 0; ks < 2; ++ks) {
    short8 pa = *(const short8*)&p_s[(wv * 16 + lr) * 72 + ks * 32 + lk8];
#pragma unroll
    for (int dt = 0; dt < 4; ++dt) {
      short8 vb = *(const short8*)&vT_s[(dt * 16 + lr) * 72 + ks * 32 + lk8];
      o[dt] = __builtin_amdgcn_mfma_f32_16x16x32_bf16(pa, vb, o[dt], 0, 0, 0);
    }
  }
  const int b = bx >> 9;
  const int head = (bx >> 6) & 7;
  const int win = bx & 63;
  const int ht = win >> 3, wt = win & 7;
#pragma unroll
  for (int r = 0; r < 4; ++r) {
    int prow = wv * 16 + lr4 + r;
    if (prow < 49) {
      int wr = prow / 7, wc = prow % 7;
      size_t gm = (size_t)b * 3136 + (ht * 7 + wr) * 56 + wt * 7 + wc;
#pragma unroll
      for (int dt = 0; dt < 4; ++dt)
        aout[gm * 512 + head * 64 + dt * 16 + lr] = f2bf(o[dt][r]);
    }
  }
}

// ---------- launcher ----------
extern "C" void kernel_launch(void* const* d_in, const int* in_sizes, int n_in,
                              void* d_out, int out_size, void* d_ws, size_t ws_size,
                              hipStream_t stream) {
  const float* x     = (const float*)d_in[0];
  const float* y     = (const float*)d_in[1];
  const float* Wq    = (const float*)d_in[2];
  const float* Wkv   = (const float*)d_in[3];
  const float* Wproj = (const float*)d_in[4];
  const float* bproj = (const float*)d_in[5];
  const float* Wsr   = (const float*)d_in[6];
  const float* bsr   = (const float*)d_in[7];
  const float* gn    = (const float*)d_in[8];
  const float* bn    = (const float*)d_in[9];
  float* out = (float*)d_out;

  char* ws = (char*)d_ws;
  unsigned short* Wq_b    = (unsigned short*)ws; ws += 524288;
  unsigned short* Wkv_b   = (unsigned short*)ws; ws += 524288;
  unsigned short* Wproj_b = (unsigned short*)ws; ws += 524288;
  unsigned short* Wsr_b   = (unsigned short*)ws; ws += 131072;
  unsigned short* regA    = (unsigned short*)ws; ws += 25690112;
  unsigned short* q_win   = (unsigned short*)ws; ws += 25690112;
  unsigned short* regC    = (unsigned short*)ws; ws += 12845056;
  unsigned short* k_win   = (unsigned short*)ws; ws += 25690112;
  unsigned short* v_win   = (unsigned short*)ws; ws += 25690112;

  cvt_all<<<13376, 256, 0, stream>>>(x, Wq, Wkv, Wproj, Wsr,
                                     regA, Wq_b, Wkv_b, Wproj_b, Wsr_b);

  // q projection -> window layout
  gemm256<512, 512, 0><<<dim3(2, 98), 512, 0, stream>>>(regA, Wq_b, q_win, nullptr, nullptr);

  // KV preprocess
  pool_cvt<<<6272, 256, 0, stream>>>(y, regA);
  sr_gemm<<<392, 256, 0, stream>>>(regA, Wsr_b, bsr, gn, bn, regC);

  // kv projection -> window layouts
  gemm256<256, 1024, 2><<<dim3(4, 98), 512, 0, stream>>>(regC, Wkv_b, k_win, nullptr, v_win);

  // windowed attention -> natural layout bf16 (reuses regA)
  attn_win<<<4096, 256, 0, stream>>>(q_win, k_win, v_win, regA);

  // output projection + bias -> f32 d_out
  gemm256<512, 512, 3><<<dim3(2, 98), 512, 0, stream>>>(regA, Wproj_b, out, bproj, nullptr);
}

// Round 6
// 171.587 us; speedup vs baseline: 1.0506x; 1.0157x over previous
//
#include <hip/hip_runtime.h>
#include <hip/hip_bf16.h>

// ---------- common ----------
typedef __attribute__((ext_vector_type(8))) short short8;
typedef __attribute__((ext_vector_type(4))) float f32x4;
typedef __attribute__((ext_vector_type(4))) unsigned short ushort4v;

#define DI __device__ __forceinline__

DI unsigned short f2bf(float f) {
  union { float f; unsigned int u; } a; a.f = f;
  unsigned int u = a.u;
  return (unsigned short)((u + 0x7FFFu + ((u >> 16) & 1u)) >> 16);
}

#define BARRIER() do { asm volatile("" ::: "memory"); __builtin_amdgcn_s_barrier(); asm volatile("" ::: "memory"); } while (0)

// Problem: B=8, H1=W1=56, N1=3136, C1=512, C2=256, NH=8, HD=64, WS=7, M=25088

// ---------- merged: 2x2 avgpool(+cvt) for y  |  weight f32->bf16 converts ----------
// blocks [0,6272): pool; [6272,7104): weights (Wq|Wkv|Wproj|Wsr concatenated)
__global__ __launch_bounds__(256)
void cvt_pool(const float* __restrict__ y, unsigned short* __restrict__ pooled,
              const float* __restrict__ Wq, const float* __restrict__ Wkv,
              const float* __restrict__ Wproj, const float* __restrict__ Wsr,
              unsigned short* __restrict__ Wq_b, unsigned short* __restrict__ Wkv_b,
              unsigned short* __restrict__ Wproj_b, unsigned short* __restrict__ Wsr_b) {
  int bid = blockIdx.x;
  if (bid < 6272) {
    int t = bid * 256 + threadIdx.x;
    int cv = (t & 63) * 4;
    int bp = t >> 6;
    int b = bp / 3136, p = bp % 3136;
    int hp = p / 56, wp = p % 56;
    const float* src = y + (((size_t)b * 12544) + hp * 224 + wp * 2) * 256 + cv;
    float4 a0 = *(const float4*)(src);
    float4 a1 = *(const float4*)(src + 256);
    float4 a2 = *(const float4*)(src + 28672);
    float4 a3 = *(const float4*)(src + 28672 + 256);
    float4 av;
    av.x = (a0.x + a1.x + a2.x + a3.x) * 0.25f;
    av.y = (a0.y + a1.y + a2.y + a3.y) * 0.25f;
    av.z = (a0.z + a1.z + a2.z + a3.z) * 0.25f;
    av.w = (a0.w + a1.w + a2.w + a3.w) * 0.25f;
    ushort4v o = { f2bf(av.x), f2bf(av.y), f2bf(av.z), f2bf(av.w) };
    *(ushort4v*)&pooled[(size_t)bp * 256 + cv] = o;
  } else {
    long i = (long)(bid - 6272) * 1024 + threadIdx.x * 4;
    const float* src; unsigned short* dst; long off;
    if (i < 262144L)      { src = Wq;    dst = Wq_b;    off = i; }
    else if (i < 524288L) { src = Wkv;   dst = Wkv_b;   off = i - 262144L; }
    else if (i < 786432L) { src = Wproj; dst = Wproj_b; off = i - 524288L; }
    else                  { src = Wsr;   dst = Wsr_b;   off = i - 786432L; }
    float4 v = *(const float4*)&src[off];
    ushort4v o = { f2bf(v.x), f2bf(v.y), f2bf(v.z), f2bf(v.w) };
    *(ushort4v*)&dst[off] = o;
  }
}

// ---------- fused 1x1 conv GEMM -> +bias -> LN -> GELU (swizzled LDS staging) ----------
__global__ __launch_bounds__(256)
void sr_gemm(const unsigned short* __restrict__ Ap, const unsigned short* __restrict__ Wsr_b,
             const float* __restrict__ bsr, const float* __restrict__ gn,
             const float* __restrict__ bn, unsigned short* __restrict__ out) {
  __shared__ unsigned short sA[64 * 64];
  __shared__ unsigned short sB[256 * 64];
  __shared__ float red[64 * 8];

  const int tid = threadIdx.x;
  const int wv = tid >> 6;
  const int lane = tid & 63;
  const int lr = lane & 15;
  const int lg = lane >> 4;
  const int lr4 = lg * 4;
  const int m0 = blockIdx.x * 64;
  const int sr8 = lane >> 3;
  const int sl8 = lane & 7;

  f32x4 acc[4][4];
#pragma unroll
  for (int i = 0; i < 4; ++i)
#pragma unroll
    for (int j = 0; j < 4; ++j) acc[i][j] = (f32x4){0.f, 0.f, 0.f, 0.f};

  for (int kt = 0; kt < 256; kt += 64) {
#pragma unroll
    for (int c = 0; c < 2; ++c) {
      int row = wv * 16 + c * 8 + sr8;
      __builtin_amdgcn_global_load_lds(
          (const __attribute__((address_space(1))) void*)
              (Ap + (size_t)(m0 + row) * 256 + kt + ((sl8 ^ (row & 7)) * 8)),
          (__attribute__((address_space(3))) void*)&sA[(wv * 16 + c * 8) * 64], 16, 0, 0);
    }
#pragma unroll
    for (int c = 0; c < 8; ++c) {
      int row = wv * 64 + c * 8 + sr8;
      __builtin_amdgcn_global_load_lds(
          (const __attribute__((address_space(1))) void*)
              (Wsr_b + (size_t)row * 256 + kt + ((sl8 ^ (row & 7)) * 8)),
          (__attribute__((address_space(3))) void*)&sB[(wv * 64 + c * 8) * 64], 16, 0, 0);
    }
    __syncthreads();
#pragma unroll
    for (int ks = 0; ks < 2; ++ks) {
      short8 af[4], bfr[4];
#pragma unroll
      for (int i = 0; i < 4; ++i)
        af[i] = *(const short8*)&sA[(i * 16 + lr) * 64 + (((ks * 4 + lg) ^ (lr & 7)) * 8)];
#pragma unroll
      for (int j = 0; j < 4; ++j)
        bfr[j] = *(const short8*)&sB[(wv * 64 + j * 16 + lr) * 64 + (((ks * 4 + lg) ^ (lr & 7)) * 8)];
#pragma unroll
      for (int i = 0; i < 4; ++i)
#pragma unroll
        for (int j = 0; j < 4; ++j)
          acc[i][j] = __builtin_amdgcn_mfma_f32_16x16x32_bf16(af[i], bfr[j], acc[i][j], 0, 0, 0);
    }
    __syncthreads();
  }

  float bsv[4], gnv[4], bnv[4];
#pragma unroll
  for (int j = 0; j < 4; ++j) {
    int col = wv * 64 + j * 16 + lr;
    bsv[j] = bsr[col]; gnv[j] = gn[col]; bnv[j] = bn[col];
  }
  float s_[4][4], q_[4][4];
#pragma unroll
  for (int i = 0; i < 4; ++i)
#pragma unroll
    for (int r = 0; r < 4; ++r) {
      float s = 0.f, q = 0.f;
#pragma unroll
      for (int j = 0; j < 4; ++j) {
        float v = acc[i][j][r] + bsv[j];
        acc[i][j][r] = v;
        s += v; q += v * v;
      }
      s_[i][r] = s; q_[i][r] = q;
    }
#pragma unroll
  for (int m = 1; m <= 8; m <<= 1)
#pragma unroll
    for (int i = 0; i < 4; ++i)
#pragma unroll
      for (int r = 0; r < 4; ++r) {
        s_[i][r] += __shfl_xor(s_[i][r], m);
        q_[i][r] += __shfl_xor(q_[i][r], m);
      }
  if (lr == 0) {
#pragma unroll
    for (int i = 0; i < 4; ++i)
#pragma unroll
      for (int r = 0; r < 4; ++r) {
        int row = i * 16 + lr4 + r;
        red[row * 8 + wv * 2 + 0] = s_[i][r];
        red[row * 8 + wv * 2 + 1] = q_[i][r];
      }
  }
  __syncthreads();
#pragma unroll
  for (int i = 0; i < 4; ++i) {
#pragma unroll
    for (int r = 0; r < 4; ++r) {
      int row = i * 16 + lr4 + r;
      float sum = red[row * 8 + 0] + red[row * 8 + 2] + red[row * 8 + 4] + red[row * 8 + 6];
      float sq  = red[row * 8 + 1] + red[row * 8 + 3] + red[row * 8 + 5] + red[row * 8 + 7];
      float mean = sum * (1.f / 256.f);
      float var = sq * (1.f / 256.f) - mean * mean;
      float rstd = rsqrtf(var + 1e-5f);
#pragma unroll
      for (int j = 0; j < 4; ++j) {
        float t = (acc[i][j][r] - mean) * rstd * gnv[j] + bnv[j];
        t = 0.5f * t * (1.f + erff(t * 0.70710678118654752f));
        out[(size_t)(m0 + row) * 256 + wv * 64 + j * 16 + lr] = f2bf(t);
      }
    }
  }
}

// ---------- epilogue helper shared by the 256-tile GEMMs ----------
template<int N, int EPI>
DI void epi_store(int gm, int gc, float v, void* outp, const float* bias, unsigned short* out2) {
  if constexpr (EPI == 3) {
    ((float*)outp)[(size_t)gm * N + gc] = v + bias[gc];
  } else if constexpr (EPI == 0) {
    const int b = gm / 3136, pos = gm % 3136;
    const int h = pos / 56, ww = pos % 56;
    const int head = gc >> 6, d = gc & 63;
    const size_t idx = ((((size_t)(b * 8 + head)) * 64 + (h / 7) * 8 + (ww / 7)) * 49
                        + (h % 7) * 7 + (ww % 7)) * 64 + d;
    ((unsigned short*)outp)[idx] = f2bf(v);
  } else { // EPI == 2
    const int b = gm / 3136, pos = gm % 3136;
    const int h = pos / 56, ww = pos % 56;
    const int sel = gc >> 9, cc = gc & 511;
    const int head = cc >> 6, d = cc & 63;
    unsigned short* dst = sel ? out2 : (unsigned short*)outp;
    const size_t idx = ((((size_t)(b * 8 + head)) * 64 + (h / 7) * 8 + (ww / 7)) * 49
                        + (h % 7) * 7 + (ww % 7)) * 64 + d;
    dst[idx] = f2bf(v);
  }
}

// ---------- 256x256 8-wave pipelined GEMM, bf16 A (gload_lds) ----------
template<int K, int N, int EPI>
__global__ __launch_bounds__(512, 2)
void gemm256(const unsigned short* __restrict__ A,
             const unsigned short* __restrict__ Bw,
             void* __restrict__ outp,
             const float* __restrict__ bias,
             unsigned short* __restrict__ out2) {
  __shared__ unsigned short lds[65536];
  const int tid = threadIdx.x;
  const int wv = tid >> 6;
  const int lane = tid & 63;
  const int wm = wv >> 2;
  const int wn = wv & 3;
  const int m0 = blockIdx.y * 256;
  const int n0 = blockIdx.x * 256;
  const int lr = lane & 15;
  const int lg = lane >> 4;
  const int lr4 = lg * 4;
  const int srow8 = lane >> 3;
  const int sl8 = lane & 7;
  constexpr int NT = K / 64;

  f32x4 acc[8][4];
#pragma unroll
  for (int i = 0; i < 8; ++i)
#pragma unroll
    for (int j = 0; j < 4; ++j) acc[i][j] = (f32x4){0.f, 0.f, 0.f, 0.f};

  auto stageA = [&](int t1, int rr) {
    int tsrc = (t1 < NT) ? t1 : NT - 1;
    int trow = rr * 64 + wv * 8 + srow8;
    int sx = sl8 ^ (trow & 7);
    __builtin_amdgcn_global_load_lds(
        (const __attribute__((address_space(1))) void*)(A + (size_t)(m0 + trow) * K + tsrc * 64 + sx * 8),
        (__attribute__((address_space(3))) void*)&lds[(t1 & 1) * 32768 + (rr * 64 + wv * 8) * 64],
        16, 0, 0);
  };
  auto stageB = [&](int t1, int rr) {
    int tsrc = (t1 < NT) ? t1 : NT - 1;
    int trow = rr * 64 + wv * 8 + srow8;
    int sx = sl8 ^ (trow & 7);
    __builtin_amdgcn_global_load_lds(
        (const __attribute__((address_space(1))) void*)(Bw + (size_t)(n0 + trow) * K + tsrc * 64 + sx * 8),
        (__attribute__((address_space(3))) void*)&lds[(t1 & 1) * 32768 + 16384 + (rr * 64 + wv * 8) * 64],
        16, 0, 0);
  };
  auto rdA = [&](int s, int mf, int ks) -> short8 {
    int row = wm * 128 + mf * 16 + lr;
    int slot = ((ks << 2) + lg) ^ (row & 7);
    return *(const short8*)&lds[s * 32768 + row * 64 + slot * 8];
  };
  auto rdB = [&](int s, int nf, int ks) -> short8 {
    int row = wn * 64 + nf * 16 + lr;
    int slot = ((ks << 2) + lg) ^ (row & 7);
    return *(const short8*)&lds[s * 32768 + 16384 + row * 64 + slot * 8];
  };

  stageA(0, 0); stageA(0, 2);
  stageB(0, 0); stageB(0, 1); stageB(0, 2); stageB(0, 3);
  stageA(0, 1); stageA(0, 3);
  asm volatile("s_waitcnt vmcnt(2)" ::: "memory");
  BARRIER();

  for (int t = 0; t < NT; ++t) {
    const int s = t & 1;
    short8 bfr[4][2];
    stageA(t + 1, 0); stageA(t + 1, 2);
#pragma unroll
    for (int j = 0; j < 4; ++j) { bfr[j][0] = rdB(s, j, 0); bfr[j][1] = rdB(s, j, 1); }
    {
      short8 x0 = rdA(s, 0, 0), x1 = rdA(s, 0, 1);
      short8 y0 = rdA(s, 1, 0), y1 = rdA(s, 1, 1);
      BARRIER();
      __builtin_amdgcn_s_setprio(1);
#pragma unroll
      for (int j = 0; j < 4; ++j) {
        acc[0][j] = __builtin_amdgcn_mfma_f32_16x16x32_bf16(x0, bfr[j][0], acc[0][j], 0, 0, 0);
        acc[0][j] = __builtin_amdgcn_mfma_f32_16x16x32_bf16(x1, bfr[j][1], acc[0][j], 0, 0, 0);
        acc[1][j] = __builtin_amdgcn_mfma_f32_16x16x32_bf16(y0, bfr[j][0], acc[1][j], 0, 0, 0);
        acc[1][j] = __builtin_amdgcn_mfma_f32_16x16x32_bf16(y1, bfr[j][1], acc[1][j], 0, 0, 0);
      }
      __builtin_amdgcn_s_setprio(0);
      BARRIER();
    }
    stageB(t + 1, 0); stageB(t + 1, 1);
    {
      short8 x0 = rdA(s, 2, 0), x1 = rdA(s, 2, 1);
      short8 y0 = rdA(s, 3, 0), y1 = rdA(s, 3, 1);
      BARRIER();
      __builtin_amdgcn_s_setprio(1);
#pragma unroll
      for (int j = 0; j < 4; ++j) {
        acc[2][j] = __builtin_amdgcn_mfma_f32_16x16x32_bf16(x0, bfr[j][0], acc[2][j], 0, 0, 0);
        acc[2][j] = __builtin_amdgcn_mfma_f32_16x16x32_bf16(x1, bfr[j][1], acc[2][j], 0, 0, 0);
        acc[3][j] = __builtin_amdgcn_mfma_f32_16x16x32_bf16(y0, bfr[j][0], acc[3][j], 0, 0, 0);
        acc[3][j] = __builtin_amdgcn_mfma_f32_16x16x32_bf16(y1, bfr[j][1], acc[3][j], 0, 0, 0);
      }
      __builtin_amdgcn_s_setprio(0);
      asm volatile("s_waitcnt vmcnt(4)" ::: "memory");
      BARRIER();
    }
    stageB(t + 1, 2); stageB(t + 1, 3);
    {
      short8 x0 = rdA(s, 4, 0), x1 = rdA(s, 4, 1);
      short8 y0 = rdA(s, 5, 0), y1 = rdA(s, 5, 1);
      BARRIER();
      __builtin_amdgcn_s_setprio(1);
#pragma unroll
      for (int j = 0; j < 4; ++j) {
        acc[4][j] = __builtin_amdgcn_mfma_f32_16x16x32_bf16(x0, bfr[j][0], acc[4][j], 0, 0, 0);
        acc[4][j] = __builtin_amdgcn_mfma_f32_16x16x32_bf16(x1, bfr[j][1], acc[4][j], 0, 0, 0);
        acc[5][j] = __builtin_amdgcn_mfma_f32_16x16x32_bf16(y0, bfr[j][0], acc[5][j], 0, 0, 0);
        acc[5][j] = __builtin_amdgcn_mfma_f32_16x16x32_bf16(y1, bfr[j][1], acc[5][j], 0, 0, 0);
      }
      __builtin_amdgcn_s_setprio(0);
      BARRIER();
    }
    stageA(t + 1, 1); stageA(t + 1, 3);
    {
      short8 x0 = rdA(s, 6, 0), x1 = rdA(s, 6, 1);
      short8 y0 = rdA(s, 7, 0), y1 = rdA(s, 7, 1);
      BARRIER();
      __builtin_amdgcn_s_setprio(1);
#pragma unroll
      for (int j = 0; j < 4; ++j) {
        acc[6][j] = __builtin_amdgcn_mfma_f32_16x16x32_bf16(x0, bfr[j][0], acc[6][j], 0, 0, 0);
        acc[6][j] = __builtin_amdgcn_mfma_f32_16x16x32_bf16(x1, bfr[j][1], acc[6][j], 0, 0, 0);
        acc[7][j] = __builtin_amdgcn_mfma_f32_16x16x32_bf16(y0, bfr[j][0], acc[7][j], 0, 0, 0);
        acc[7][j] = __builtin_amdgcn_mfma_f32_16x16x32_bf16(y1, bfr[j][1], acc[7][j], 0, 0, 0);
      }
      __builtin_amdgcn_s_setprio(0);
      asm volatile("s_waitcnt vmcnt(2)" ::: "memory");
      BARRIER();
    }
  }

#pragma unroll
  for (int i = 0; i < 8; ++i)
#pragma unroll
    for (int j = 0; j < 4; ++j)
#pragma unroll
      for (int r = 0; r < 4; ++r)
        epi_store<N, EPI>(m0 + wm * 128 + i * 16 + lr4 + r, n0 + wn * 64 + j * 16 + lr,
                          acc[i][j][r], outp, bias, out2);
}

// ---------- 256x256 GEMM, f32 A reg-staged (fused x->bf16 convert) ----------
template<int K, int N, int EPI>
__global__ __launch_bounds__(512, 2)
void gemm256f(const float* __restrict__ A,
              const unsigned short* __restrict__ Bw,
              void* __restrict__ outp,
              const float* __restrict__ bias,
              unsigned short* __restrict__ out2) {
  __shared__ unsigned short lds[65536];
  const int tid = threadIdx.x;
  const int wv = tid >> 6;
  const int lane = tid & 63;
  const int wm = wv >> 2;
  const int wn = wv & 3;
  const int m0 = blockIdx.y * 256;
  const int n0 = blockIdx.x * 256;
  const int lr = lane & 15;
  const int lg = lane >> 4;
  const int lr4 = lg * 4;
  const int srow8 = lane >> 3;
  const int sl8 = lane & 7;
  constexpr int NT = K / 64;

  f32x4 acc[8][4];
#pragma unroll
  for (int i = 0; i < 8; ++i)
#pragma unroll
    for (int j = 0; j < 4; ++j) acc[i][j] = (f32x4){0.f, 0.f, 0.f, 0.f};

  float4 fa[4][2];
  auto loadA = [&](int t1) {
    int tsrc = (t1 < NT) ? t1 : NT - 1;
#pragma unroll
    for (int rr = 0; rr < 4; ++rr) {
      int trow = rr * 64 + wv * 8 + srow8;
      const float* p = A + (size_t)(m0 + trow) * K + tsrc * 64 + sl8 * 8;
      fa[rr][0] = *(const float4*)p;
      fa[rr][1] = *(const float4*)(p + 4);
    }
    asm volatile("" ::: "memory");  // pin issue order vs subsequent gload_lds
  };
  auto writeA = [&](int t1) {
#pragma unroll
    for (int rr = 0; rr < 4; ++rr) {
      int trow = rr * 64 + wv * 8 + srow8;
      union { short8 s; unsigned short u[8]; } w;
      w.u[0] = f2bf(fa[rr][0].x); w.u[1] = f2bf(fa[rr][0].y);
      w.u[2] = f2bf(fa[rr][0].z); w.u[3] = f2bf(fa[rr][0].w);
      w.u[4] = f2bf(fa[rr][1].x); w.u[5] = f2bf(fa[rr][1].y);
      w.u[6] = f2bf(fa[rr][1].z); w.u[7] = f2bf(fa[rr][1].w);
      *(short8*)&lds[(t1 & 1) * 32768 + trow * 64 + ((sl8 ^ (trow & 7)) * 8)] = w.s;
    }
  };
  auto stageB = [&](int t1, int rr) {
    int tsrc = (t1 < NT) ? t1 : NT - 1;
    int trow = rr * 64 + wv * 8 + srow8;
    int sx = sl8 ^ (trow & 7);
    __builtin_amdgcn_global_load_lds(
        (const __attribute__((address_space(1))) void*)(Bw + (size_t)(n0 + trow) * K + tsrc * 64 + sx * 8),
        (__attribute__((address_space(3))) void*)&lds[(t1 & 1) * 32768 + 16384 + (rr * 64 + wv * 8) * 64],
        16, 0, 0);
  };
  auto rdA = [&](int s, int mf, int ks) -> short8 {
    int row = wm * 128 + mf * 16 + lr;
    int slot = ((ks << 2) + lg) ^ (row & 7);
    return *(const short8*)&lds[s * 32768 + row * 64 + slot * 8];
  };
  auto rdB = [&](int s, int nf, int ks) -> short8 {
    int row = wn * 64 + nf * 16 + lr;
    int slot = ((ks << 2) + lg) ^ (row & 7);
    return *(const short8*)&lds[s * 32768 + 16384 + row * 64 + slot * 8];
  };

  // Prologue: B(0) via gload_lds, A(0) via regs; full drain once, write slot 0.
  stageB(0, 0); stageB(0, 1); stageB(0, 2); stageB(0, 3);
  loadA(0);
  asm volatile("s_waitcnt vmcnt(0)" ::: "memory");
  writeA(0);
  asm volatile("s_waitcnt lgkmcnt(0)" ::: "memory");
  BARRIER();

  for (int t = 0; t < NT; ++t) {
    const int s = t & 1;
    short8 bfr[4][2];
    // phase 0: issue A(t+1) f32 loads (oldest in vm queue); B frags + m0,m1
    loadA(t + 1);
#pragma unroll
    for (int j = 0; j < 4; ++j) { bfr[j][0] = rdB(s, j, 0); bfr[j][1] = rdB(s, j, 1); }
    {
      short8 x0 = rdA(s, 0, 0), x1 = rdA(s, 0, 1);
      short8 y0 = rdA(s, 1, 0), y1 = rdA(s, 1, 1);
      BARRIER();
      __builtin_amdgcn_s_setprio(1);
#pragma unroll
      for (int j = 0; j < 4; ++j) {
        acc[0][j] = __builtin_amdgcn_mfma_f32_16x16x32_bf16(x0, bfr[j][0], acc[0][j], 0, 0, 0);
        acc[0][j] = __builtin_amdgcn_mfma_f32_16x16x32_bf16(x1, bfr[j][1], acc[0][j], 0, 0, 0);
        acc[1][j] = __builtin_amdgcn_mfma_f32_16x16x32_bf16(y0, bfr[j][0], acc[1][j], 0, 0, 0);
        acc[1][j] = __builtin_amdgcn_mfma_f32_16x16x32_bf16(y1, bfr[j][1], acc[1][j], 0, 0, 0);
      }
      __builtin_amdgcn_s_setprio(0);
      BARRIER();
    }
    // phase 1
    stageB(t + 1, 0); stageB(t + 1, 1);
    {
      short8 x0 = rdA(s, 2, 0), x1 = rdA(s, 2, 1);
      short8 y0 = rdA(s, 3, 0), y1 = rdA(s, 3, 1);
      BARRIER();
      __builtin_amdgcn_s_setprio(1);
#pragma unroll
      for (int j = 0; j < 4; ++j) {
        acc[2][j] = __builtin_amdgcn_mfma_f32_16x16x32_bf16(x0, bfr[j][0], acc[2][j], 0, 0, 0);
        acc[2][j] = __builtin_amdgcn_mfma_f32_16x16x32_bf16(x1, bfr[j][1], acc[2][j], 0, 0, 0);
        acc[3][j] = __builtin_amdgcn_mfma_f32_16x16x32_bf16(y0, bfr[j][0], acc[3][j], 0, 0, 0);
        acc[3][j] = __builtin_amdgcn_mfma_f32_16x16x32_bf16(y1, bfr[j][1], acc[3][j], 0, 0, 0);
      }
      __builtin_amdgcn_s_setprio(0);
      BARRIER();
    }
    // phase 2
    stageB(t + 1, 2); stageB(t + 1, 3);
    {
      short8 x0 = rdA(s, 4, 0), x1 = rdA(s, 4, 1);
      short8 y0 = rdA(s, 5, 0), y1 = rdA(s, 5, 1);
      BARRIER();
      __builtin_amdgcn_s_setprio(1);
#pragma unroll
      for (int j = 0; j < 4; ++j) {
        acc[4][j] = __builtin_amdgcn_mfma_f32_16x16x32_bf16(x0, bfr[j][0], acc[4][j], 0, 0, 0);
        acc[4][j] = __builtin_amdgcn_mfma_f32_16x16x32_bf16(x1, bfr[j][1], acc[4][j], 0, 0, 0);
        acc[5][j] = __builtin_amdgcn_mfma_f32_16x16x32_bf16(y0, bfr[j][0], acc[5][j], 0, 0, 0);
        acc[5][j] = __builtin_amdgcn_mfma_f32_16x16x32_bf16(y1, bfr[j][1], acc[5][j], 0, 0, 0);
      }
      __builtin_amdgcn_s_setprio(0);
      BARRIER();
    }
    // phase 3: m6,m7 reads (slot s); retire A(t+1) regs (vmcnt: 8A oldest + 4B newest -> 4);
    // cvt+write A(t+1) to slot s^1; boundary drains B(t+1).
    {
      short8 x0 = rdA(s, 6, 0), x1 = rdA(s, 6, 1);
      short8 y0 = rdA(s, 7, 0), y1 = rdA(s, 7, 1);
      asm volatile("s_waitcnt vmcnt(4)" ::: "memory");
      writeA(t + 1);
      asm volatile("s_waitcnt lgkmcnt(0)" ::: "memory");
      BARRIER();
      __builtin_amdgcn_s_setprio(1);
#pragma unroll
      for (int j = 0; j < 4; ++j) {
        acc[6][j] = __builtin_amdgcn_mfma_f32_16x16x32_bf16(x0, bfr[j][0], acc[6][j], 0, 0, 0);
        acc[6][j] = __builtin_amdgcn_mfma_f32_16x16x32_bf16(x1, bfr[j][1], acc[6][j], 0, 0, 0);
        acc[7][j] = __builtin_amdgcn_mfma_f32_16x16x32_bf16(y0, bfr[j][0], acc[7][j], 0, 0, 0);
        acc[7][j] = __builtin_amdgcn_mfma_f32_16x16x32_bf16(y1, bfr[j][1], acc[7][j], 0, 0, 0);
      }
      __builtin_amdgcn_s_setprio(0);
      asm volatile("s_waitcnt vmcnt(0)" ::: "memory");
      BARRIER();
    }
  }

#pragma unroll
  for (int i = 0; i < 8; ++i)
#pragma unroll
    for (int j = 0; j < 4; ++j)
#pragma unroll
      for (int r = 0; r < 4; ++r)
        epi_store<N, EPI>(m0 + wm * 128 + i * 16 + lr4 + r, n0 + wn * 64 + j * 16 + lr,
                          acc[i][j][r], outp, bias, out2);
}

// ---------- windowed attention (conflict-free LDS) ----------
__global__ __launch_bounds__(256)
void attn_win(const unsigned short* __restrict__ qw,
              const unsigned short* __restrict__ kw,
              const unsigned short* __restrict__ vw,
              unsigned short* __restrict__ aout) {
  __shared__ unsigned short q_s[64 * 72];
  __shared__ unsigned short k_s[64 * 72];
  __shared__ unsigned short vT_s[64 * 72];
  __shared__ unsigned short p_s[64 * 72];

  const int tid = threadIdx.x;
  const int bx = blockIdx.x;
  const int wv = tid >> 6;
  const int lane = tid & 63;
  const int lr = lane & 15;
  const int lg = lane >> 4;
  const int lk8 = lg * 8;
  const int lr4 = lg * 4;

  const size_t base = (size_t)bx * 3136;
  for (int i = tid * 8; i < 4096; i += 2048) {
    int row = i >> 6, col = i & 63;
    uint4 zv = make_uint4(0u, 0u, 0u, 0u);
    uint4 qv = zv, kvv = zv;
    if (i < 3136) {
      qv  = *(const uint4*)&qw[base + i];
      kvv = *(const uint4*)&kw[base + i];
    }
    *(uint4*)&q_s[row * 72 + col] = qv;
    *(uint4*)&k_s[row * 72 + col] = kvv;
  }
  for (int i = tid * 8; i < 4096; i += 2048) {
    int j = i >> 6, d0 = i & 63;
    union { uint4 v; unsigned short u[8]; } t;
    t.v = make_uint4(0u, 0u, 0u, 0u);
    if (i < 3136) t.v = *(const uint4*)&vw[base + i];
#pragma unroll
    for (int e = 0; e < 8; ++e) {
      int d = d0 + e;
      vT_s[d * 72 + (j ^ (((d >> 3) & 7) << 3))] = t.u[e];
    }
  }
  __syncthreads();

  f32x4 s[4];
#pragma unroll
  for (int j = 0; j < 4; ++j) s[j] = (f32x4){0.f, 0.f, 0.f, 0.f};
#pragma unroll
  for (int ks = 0; ks < 2; ++ks) {
    short8 aq = *(const short8*)&q_s[(wv * 16 + lr) * 72 + ks * 32 + lk8];
#pragma unroll
    for (int j = 0; j < 4; ++j) {
      short8 bk = *(const short8*)&k_s[(j * 16 + lr) * 72 + ks * 32 + lk8];
      s[j] = __builtin_amdgcn_mfma_f32_16x16x32_bf16(aq, bk, s[j], 0, 0, 0);
    }
  }
#pragma unroll
  for (int j = 0; j < 4; ++j) {
    if (j * 16 + lr >= 49) {
#pragma unroll
      for (int r = 0; r < 4; ++r) s[j][r] = -1e30f;
    }
  }
  float mx[4], sm[4];
#pragma unroll
  for (int r = 0; r < 4; ++r)
    mx[r] = fmaxf(fmaxf(s[0][r], s[1][r]), fmaxf(s[2][r], s[3][r]));
#pragma unroll
  for (int m = 1; m <= 8; m <<= 1)
#pragma unroll
    for (int r = 0; r < 4; ++r) mx[r] = fmaxf(mx[r], __shfl_xor(mx[r], m));
  const float cexp = 0.125f * 1.4426950408889634f;
  float pv[4][4];
#pragma unroll
  for (int j = 0; j < 4; ++j)
#pragma unroll
    for (int r = 0; r < 4; ++r)
      pv[j][r] = exp2f((s[j][r] - mx[r]) * cexp);
#pragma unroll
  for (int r = 0; r < 4; ++r)
    sm[r] = pv[0][r] + pv[1][r] + pv[2][r] + pv[3][r];
#pragma unroll
  for (int m = 1; m <= 8; m <<= 1)
#pragma unroll
    for (int r = 0; r < 4; ++r) sm[r] += __shfl_xor(sm[r], m);
#pragma unroll
  for (int r = 0; r < 4; ++r) sm[r] = 1.f / sm[r];
#pragma unroll
  for (int j = 0; j < 4; ++j)
#pragma unroll
    for (int r = 0; r < 4; ++r)
      p_s[(wv * 16 + lr4 + r) * 72 + j * 16 + lr] = f2bf(pv[j][r] * sm[r]);
  __syncthreads();

  f32x4 o[4];
#pragma unroll
  for (int dt = 0; dt < 4; ++dt) o[dt] = (f32x4){0.f, 0.f, 0.f, 0.f};
#pragma unroll
  for (int ks = 0; ks < 2; ++ks) {
    short8 pa = *(const short8*)&p_s[(wv * 16 + lr) * 72 + ks * 32 + lk8];
#pragma unroll
    for (int dt = 0; dt < 4; ++dt) {
      int row = dt * 16 + lr;
      int cb = (ks * 4 + lg) ^ ((row >> 3) & 7);
      short8 vb = *(const short8*)&vT_s[row * 72 + cb * 8];
      o[dt] = __builtin_amdgcn_mfma_f32_16x16x32_bf16(pa, vb, o[dt], 0, 0, 0);
    }
  }
  const int b = bx >> 9;
  const int head = (bx >> 6) & 7;
  const int win = bx & 63;
  const int ht = win >> 3, wt = win & 7;
#pragma unroll
  for (int r = 0; r < 4; ++r) {
    int prow = wv * 16 + lr4 + r;
    if (prow < 49) {
      int wr = prow / 7, wc = prow % 7;
      size_t gm = (size_t)b * 3136 + (ht * 7 + wr) * 56 + wt * 7 + wc;
#pragma unroll
      for (int dt = 0; dt < 4; ++dt)
        aout[gm * 512 + head * 64 + dt * 16 + lr] = f2bf(o[dt][r]);
    }
  }
}

// ---------- launcher ----------
extern "C" void kernel_launch(void* const* d_in, const int* in_sizes, int n_in,
                              void* d_out, int out_size, void* d_ws, size_t ws_size,
                              hipStream_t stream) {
  const float* x     = (const float*)d_in[0];
  const float* y     = (const float*)d_in[1];
  const float* Wq    = (const float*)d_in[2];
  const float* Wkv   = (const float*)d_in[3];
  const float* Wproj = (const float*)d_in[4];
  const float* bproj = (const float*)d_in[5];
  const float* Wsr   = (const float*)d_in[6];
  const float* bsr   = (const float*)d_in[7];
  const float* gn    = (const float*)d_in[8];
  const float* bn    = (const float*)d_in[9];
  float* out = (float*)d_out;

  char* ws = (char*)d_ws;
  unsigned short* Wq_b    = (unsigned short*)ws; ws += 524288;
  unsigned short* Wkv_b   = (unsigned short*)ws; ws += 524288;
  unsigned short* Wproj_b = (unsigned short*)ws; ws += 524288;
  unsigned short* Wsr_b   = (unsigned short*)ws; ws += 131072;
  unsigned short* regA    = (unsigned short*)ws; ws += 25690112; // pooled bf16 -> attn out
  unsigned short* q_win   = (unsigned short*)ws; ws += 25690112;
  unsigned short* regC    = (unsigned short*)ws; ws += 12845056; // y2 bf16
  unsigned short* k_win   = (unsigned short*)ws; ws += 25690112;
  unsigned short* v_win   = (unsigned short*)ws; ws += 25690112;

  // pool y -> regA (bf16)  |  weight converts (one launch)
  cvt_pool<<<7104, 256, 0, stream>>>(y, regA, Wq, Wkv, Wproj, Wsr,
                                     Wq_b, Wkv_b, Wproj_b, Wsr_b);

  // q projection (x read f32 directly, cvt fused into staging) -> window layout
  gemm256f<512, 512, 0><<<dim3(2, 98), 512, 0, stream>>>(x, Wq_b, q_win, nullptr, nullptr);

  // fused conv+bias+LN+GELU
  sr_gemm<<<392, 256, 0, stream>>>(regA, Wsr_b, bsr, gn, bn, regC);

  // kv projection -> window layouts
  gemm256<256, 1024, 2><<<dim3(4, 98), 512, 0, stream>>>(regC, Wkv_b, k_win, nullptr, v_win);

  // windowed attention -> natural layout bf16 (reuses regA)
  attn_win<<<4096, 256, 0, stream>>>(q_win, k_win, v_win, regA);

  // output projection + bias -> f32 d_out
  gemm256<512, 512, 3><<<dim3(2, 98), 512, 0, stream>>>(regA, Wproj_b, out, bproj, nullptr);
}

// Round 7
// 160.601 us; speedup vs baseline: 1.1225x; 1.0684x over previous
//
#include <hip/hip_runtime.h>
#include <hip/hip_bf16.h>

// ---------- common ----------
typedef __attribute__((ext_vector_type(8))) short short8;
typedef __attribute__((ext_vector_type(4))) float f32x4;
typedef __attribute__((ext_vector_type(4))) unsigned short ushort4v;

#define DI __device__ __forceinline__

DI unsigned short f2bf(float f) {
  union { float f; unsigned int u; } a; a.f = f;
  unsigned int u = a.u;
  return (unsigned short)((u + 0x7FFFu + ((u >> 16) & 1u)) >> 16);
}

#define BARRIER() do { asm volatile("" ::: "memory"); __builtin_amdgcn_s_barrier(); asm volatile("" ::: "memory"); } while (0)
#define GLOAD16(src, dst) __builtin_amdgcn_global_load_lds( \
    (const __attribute__((address_space(1))) void*)(src), \
    (__attribute__((address_space(3))) void*)(dst), 16, 0, 0)

// Problem: B=8, H1=W1=56, N1=3136, C1=512, C2=256, NH=8, HD=64, WS=7, M=25088

// ---------- merged: 2x2 avgpool(+cvt) for y | weight f32->bf16 converts ----------
__global__ __launch_bounds__(256)
void cvt_pool(const float* __restrict__ y, unsigned short* __restrict__ pooled,
              const float* __restrict__ Wq, const float* __restrict__ Wkv,
              const float* __restrict__ Wproj, const float* __restrict__ Wsr,
              unsigned short* __restrict__ Wq_b, unsigned short* __restrict__ Wkv_b,
              unsigned short* __restrict__ Wproj_b, unsigned short* __restrict__ Wsr_b) {
  int bid = blockIdx.x;
  if (bid < 6272) {
    int t = bid * 256 + threadIdx.x;
    int cv = (t & 63) * 4;
    int bp = t >> 6;
    int b = bp / 3136, p = bp % 3136;
    int hp = p / 56, wp = p % 56;
    const float* src = y + (((size_t)b * 12544) + hp * 224 + wp * 2) * 256 + cv;
    float4 a0 = *(const float4*)(src);
    float4 a1 = *(const float4*)(src + 256);
    float4 a2 = *(const float4*)(src + 28672);
    float4 a3 = *(const float4*)(src + 28672 + 256);
    float4 av;
    av.x = (a0.x + a1.x + a2.x + a3.x) * 0.25f;
    av.y = (a0.y + a1.y + a2.y + a3.y) * 0.25f;
    av.z = (a0.z + a1.z + a2.z + a3.z) * 0.25f;
    av.w = (a0.w + a1.w + a2.w + a3.w) * 0.25f;
    ushort4v o = { f2bf(av.x), f2bf(av.y), f2bf(av.z), f2bf(av.w) };
    *(ushort4v*)&pooled[(size_t)bp * 256 + cv] = o;
  } else {
    long i = (long)(bid - 6272) * 1024 + threadIdx.x * 4;
    const float* src; unsigned short* dst; long off;
    if (i < 262144L)      { src = Wq;    dst = Wq_b;    off = i; }
    else if (i < 524288L) { src = Wkv;   dst = Wkv_b;   off = i - 262144L; }
    else if (i < 786432L) { src = Wproj; dst = Wproj_b; off = i - 524288L; }
    else                  { src = Wsr;   dst = Wsr_b;   off = i - 786432L; }
    float4 v = *(const float4*)&src[off];
    ushort4v o = { f2bf(v.x), f2bf(v.y), f2bf(v.z), f2bf(v.w) };
    *(ushort4v*)&dst[off] = o;
  }
}

// ---------- fused 1x1 conv GEMM -> +bias -> LN -> GELU (swizzled LDS) ----------
__global__ __launch_bounds__(256)
void sr_gemm(const unsigned short* __restrict__ Ap, const unsigned short* __restrict__ Wsr_b,
             const float* __restrict__ bsr, const float* __restrict__ gn,
             const float* __restrict__ bn, unsigned short* __restrict__ out) {
  __shared__ unsigned short sA[64 * 64];
  __shared__ unsigned short sB[256 * 64];
  __shared__ float red[64 * 8];

  const int tid = threadIdx.x;
  const int wv = tid >> 6;
  const int lane = tid & 63;
  const int lr = lane & 15;
  const int lg = lane >> 4;
  const int lr4 = lg * 4;
  const int m0 = blockIdx.x * 64;
  const int sr8 = lane >> 3;
  const int sl8 = lane & 7;

  f32x4 acc[4][4];
#pragma unroll
  for (int i = 0; i < 4; ++i)
#pragma unroll
    for (int j = 0; j < 4; ++j) acc[i][j] = (f32x4){0.f, 0.f, 0.f, 0.f};

  for (int kt = 0; kt < 256; kt += 64) {
#pragma unroll
    for (int c = 0; c < 2; ++c) {
      int row = wv * 16 + c * 8 + sr8;
      GLOAD16(Ap + (size_t)(m0 + row) * 256 + kt + ((sl8 ^ (row & 7)) * 8),
              &sA[(wv * 16 + c * 8) * 64]);
    }
#pragma unroll
    for (int c = 0; c < 8; ++c) {
      int row = wv * 64 + c * 8 + sr8;
      GLOAD16(Wsr_b + (size_t)row * 256 + kt + ((sl8 ^ (row & 7)) * 8),
              &sB[(wv * 64 + c * 8) * 64]);
    }
    __syncthreads();
#pragma unroll
    for (int ks = 0; ks < 2; ++ks) {
      short8 af[4], bfr[4];
#pragma unroll
      for (int i = 0; i < 4; ++i)
        af[i] = *(const short8*)&sA[(i * 16 + lr) * 64 + (((ks * 4 + lg) ^ (lr & 7)) * 8)];
#pragma unroll
      for (int j = 0; j < 4; ++j)
        bfr[j] = *(const short8*)&sB[(wv * 64 + j * 16 + lr) * 64 + (((ks * 4 + lg) ^ (lr & 7)) * 8)];
#pragma unroll
      for (int i = 0; i < 4; ++i)
#pragma unroll
        for (int j = 0; j < 4; ++j)
          acc[i][j] = __builtin_amdgcn_mfma_f32_16x16x32_bf16(af[i], bfr[j], acc[i][j], 0, 0, 0);
    }
    __syncthreads();
  }

  float bsv[4], gnv[4], bnv[4];
#pragma unroll
  for (int j = 0; j < 4; ++j) {
    int col = wv * 64 + j * 16 + lr;
    bsv[j] = bsr[col]; gnv[j] = gn[col]; bnv[j] = bn[col];
  }
  float s_[4][4], q_[4][4];
#pragma unroll
  for (int i = 0; i < 4; ++i)
#pragma unroll
    for (int r = 0; r < 4; ++r) {
      float s = 0.f, q = 0.f;
#pragma unroll
      for (int j = 0; j < 4; ++j) {
        float v = acc[i][j][r] + bsv[j];
        acc[i][j][r] = v;
        s += v; q += v * v;
      }
      s_[i][r] = s; q_[i][r] = q;
    }
#pragma unroll
  for (int m = 1; m <= 8; m <<= 1)
#pragma unroll
    for (int i = 0; i < 4; ++i)
#pragma unroll
      for (int r = 0; r < 4; ++r) {
        s_[i][r] += __shfl_xor(s_[i][r], m);
        q_[i][r] += __shfl_xor(q_[i][r], m);
      }
  if (lr == 0) {
#pragma unroll
    for (int i = 0; i < 4; ++i)
#pragma unroll
      for (int r = 0; r < 4; ++r) {
        int row = i * 16 + lr4 + r;
        red[row * 8 + wv * 2 + 0] = s_[i][r];
        red[row * 8 + wv * 2 + 1] = q_[i][r];
      }
  }
  __syncthreads();
#pragma unroll
  for (int i = 0; i < 4; ++i) {
#pragma unroll
    for (int r = 0; r < 4; ++r) {
      int row = i * 16 + lr4 + r;
      float sum = red[row * 8 + 0] + red[row * 8 + 2] + red[row * 8 + 4] + red[row * 8 + 6];
      float sq  = red[row * 8 + 1] + red[row * 8 + 3] + red[row * 8 + 5] + red[row * 8 + 7];
      float mean = sum * (1.f / 256.f);
      float var = sq * (1.f / 256.f) - mean * mean;
      float rstd = rsqrtf(var + 1e-5f);
#pragma unroll
      for (int j = 0; j < 4; ++j) {
        float t = (acc[i][j][r] - mean) * rstd * gnv[j] + bnv[j];
        t = 0.5f * t * (1.f + erff(t * 0.70710678118654752f));
        out[(size_t)(m0 + row) * 256 + wv * 64 + j * 16 + lr] = f2bf(t);
      }
    }
  }
}

// ---------- epilogue helper ----------
template<int N, int EPI>
DI void epi_store(int gm, int gc, float v, void* outp, const float* bias, unsigned short* out2) {
  if constexpr (EPI == 3) {
    ((float*)outp)[(size_t)gm * N + gc] = v + bias[gc];
  } else if constexpr (EPI == 0) {
    const int b = gm / 3136, pos = gm % 3136;
    const int h = pos / 56, ww = pos % 56;
    const int head = gc >> 6, d = gc & 63;
    const size_t idx = ((((size_t)(b * 8 + head)) * 64 + (h / 7) * 8 + (ww / 7)) * 49
                        + (h % 7) * 7 + (ww % 7)) * 64 + d;
    ((unsigned short*)outp)[idx] = f2bf(v);
  }
}

// ---------- 256x256 GEMM, f32 A reg-staged (fused x->bf16 convert) ----------
template<int K, int N, int EPI>
__global__ __launch_bounds__(512, 2)
void gemm256f(const float* __restrict__ A,
              const unsigned short* __restrict__ Bw,
              void* __restrict__ outp,
              const float* __restrict__ bias,
              unsigned short* __restrict__ out2) {
  __shared__ unsigned short lds[65536];
  const int tid = threadIdx.x;
  const int wv = tid >> 6;
  const int lane = tid & 63;
  const int wm = wv >> 2;
  const int wn = wv & 3;
  const int m0 = blockIdx.y * 256;
  const int n0 = blockIdx.x * 256;
  const int lr = lane & 15;
  const int lg = lane >> 4;
  const int lr4 = lg * 4;
  const int srow8 = lane >> 3;
  const int sl8 = lane & 7;
  constexpr int NT = K / 64;

  f32x4 acc[8][4];
#pragma unroll
  for (int i = 0; i < 8; ++i)
#pragma unroll
    for (int j = 0; j < 4; ++j) acc[i][j] = (f32x4){0.f, 0.f, 0.f, 0.f};

  float4 fa[4][2];
  auto loadA = [&](int t1) {
    int tsrc = (t1 < NT) ? t1 : NT - 1;
#pragma unroll
    for (int rr = 0; rr < 4; ++rr) {
      int trow = rr * 64 + wv * 8 + srow8;
      const float* p = A + (size_t)(m0 + trow) * K + tsrc * 64 + sl8 * 8;
      fa[rr][0] = *(const float4*)p;
      fa[rr][1] = *(const float4*)(p + 4);
    }
    asm volatile("" ::: "memory");
  };
  auto writeA = [&](int t1) {
#pragma unroll
    for (int rr = 0; rr < 4; ++rr) {
      int trow = rr * 64 + wv * 8 + srow8;
      union { short8 s; unsigned short u[8]; } w;
      w.u[0] = f2bf(fa[rr][0].x); w.u[1] = f2bf(fa[rr][0].y);
      w.u[2] = f2bf(fa[rr][0].z); w.u[3] = f2bf(fa[rr][0].w);
      w.u[4] = f2bf(fa[rr][1].x); w.u[5] = f2bf(fa[rr][1].y);
      w.u[6] = f2bf(fa[rr][1].z); w.u[7] = f2bf(fa[rr][1].w);
      *(short8*)&lds[(t1 & 1) * 32768 + trow * 64 + ((sl8 ^ (trow & 7)) * 8)] = w.s;
    }
  };
  auto stageB = [&](int t1, int rr) {
    int tsrc = (t1 < NT) ? t1 : NT - 1;
    int trow = rr * 64 + wv * 8 + srow8;
    int sx = sl8 ^ (trow & 7);
    GLOAD16(Bw + (size_t)(n0 + trow) * K + tsrc * 64 + sx * 8,
            &lds[(t1 & 1) * 32768 + 16384 + (rr * 64 + wv * 8) * 64]);
  };
  auto rdA = [&](int s, int mf, int ks) -> short8 {
    int row = wm * 128 + mf * 16 + lr;
    int slot = ((ks << 2) + lg) ^ (row & 7);
    return *(const short8*)&lds[s * 32768 + row * 64 + slot * 8];
  };
  auto rdB = [&](int s, int nf, int ks) -> short8 {
    int row = wn * 64 + nf * 16 + lr;
    int slot = ((ks << 2) + lg) ^ (row & 7);
    return *(const short8*)&lds[s * 32768 + 16384 + row * 64 + slot * 8];
  };

  stageB(0, 0); stageB(0, 1); stageB(0, 2); stageB(0, 3);
  loadA(0);
  asm volatile("s_waitcnt vmcnt(0)" ::: "memory");
  writeA(0);
  asm volatile("s_waitcnt lgkmcnt(0)" ::: "memory");
  BARRIER();

  for (int t = 0; t < NT; ++t) {
    const int s = t & 1;
    short8 bfr[4][2];
    loadA(t + 1);
#pragma unroll
    for (int j = 0; j < 4; ++j) { bfr[j][0] = rdB(s, j, 0); bfr[j][1] = rdB(s, j, 1); }
    {
      short8 x0 = rdA(s, 0, 0), x1 = rdA(s, 0, 1);
      short8 y0 = rdA(s, 1, 0), y1 = rdA(s, 1, 1);
      BARRIER();
      __builtin_amdgcn_s_setprio(1);
#pragma unroll
      for (int j = 0; j < 4; ++j) {
        acc[0][j] = __builtin_amdgcn_mfma_f32_16x16x32_bf16(x0, bfr[j][0], acc[0][j], 0, 0, 0);
        acc[0][j] = __builtin_amdgcn_mfma_f32_16x16x32_bf16(x1, bfr[j][1], acc[0][j], 0, 0, 0);
        acc[1][j] = __builtin_amdgcn_mfma_f32_16x16x32_bf16(y0, bfr[j][0], acc[1][j], 0, 0, 0);
        acc[1][j] = __builtin_amdgcn_mfma_f32_16x16x32_bf16(y1, bfr[j][1], acc[1][j], 0, 0, 0);
      }
      __builtin_amdgcn_s_setprio(0);
      BARRIER();
    }
    stageB(t + 1, 0); stageB(t + 1, 1);
    {
      short8 x0 = rdA(s, 2, 0), x1 = rdA(s, 2, 1);
      short8 y0 = rdA(s, 3, 0), y1 = rdA(s, 3, 1);
      BARRIER();
      __builtin_amdgcn_s_setprio(1);
#pragma unroll
      for (int j = 0; j < 4; ++j) {
        acc[2][j] = __builtin_amdgcn_mfma_f32_16x16x32_bf16(x0, bfr[j][0], acc[2][j], 0, 0, 0);
        acc[2][j] = __builtin_amdgcn_mfma_f32_16x16x32_bf16(x1, bfr[j][1], acc[2][j], 0, 0, 0);
        acc[3][j] = __builtin_amdgcn_mfma_f32_16x16x32_bf16(y0, bfr[j][0], acc[3][j], 0, 0, 0);
        acc[3][j] = __builtin_amdgcn_mfma_f32_16x16x32_bf16(y1, bfr[j][1], acc[3][j], 0, 0, 0);
      }
      __builtin_amdgcn_s_setprio(0);
      BARRIER();
    }
    stageB(t + 1, 2); stageB(t + 1, 3);
    {
      short8 x0 = rdA(s, 4, 0), x1 = rdA(s, 4, 1);
      short8 y0 = rdA(s, 5, 0), y1 = rdA(s, 5, 1);
      BARRIER();
      __builtin_amdgcn_s_setprio(1);
#pragma unroll
      for (int j = 0; j < 4; ++j) {
        acc[4][j] = __builtin_amdgcn_mfma_f32_16x16x32_bf16(x0, bfr[j][0], acc[4][j], 0, 0, 0);
        acc[4][j] = __builtin_amdgcn_mfma_f32_16x16x32_bf16(x1, bfr[j][1], acc[4][j], 0, 0, 0);
        acc[5][j] = __builtin_amdgcn_mfma_f32_16x16x32_bf16(y0, bfr[j][0], acc[5][j], 0, 0, 0);
        acc[5][j] = __builtin_amdgcn_mfma_f32_16x16x32_bf16(y1, bfr[j][1], acc[5][j], 0, 0, 0);
      }
      __builtin_amdgcn_s_setprio(0);
      BARRIER();
    }
    {
      short8 x0 = rdA(s, 6, 0), x1 = rdA(s, 6, 1);
      short8 y0 = rdA(s, 7, 0), y1 = rdA(s, 7, 1);
      asm volatile("s_waitcnt vmcnt(4)" ::: "memory");
      writeA(t + 1);
      asm volatile("s_waitcnt lgkmcnt(0)" ::: "memory");
      BARRIER();
      __builtin_amdgcn_s_setprio(1);
#pragma unroll
      for (int j = 0; j < 4; ++j) {
        acc[6][j] = __builtin_amdgcn_mfma_f32_16x16x32_bf16(x0, bfr[j][0], acc[6][j], 0, 0, 0);
        acc[6][j] = __builtin_amdgcn_mfma_f32_16x16x32_bf16(x1, bfr[j][1], acc[6][j], 0, 0, 0);
        acc[7][j] = __builtin_amdgcn_mfma_f32_16x16x32_bf16(y0, bfr[j][0], acc[7][j], 0, 0, 0);
        acc[7][j] = __builtin_amdgcn_mfma_f32_16x16x32_bf16(y1, bfr[j][1], acc[7][j], 0, 0, 0);
      }
      __builtin_amdgcn_s_setprio(0);
      asm volatile("s_waitcnt vmcnt(0)" ::: "memory");
      BARRIER();
    }
  }

#pragma unroll
  for (int i = 0; i < 8; ++i)
#pragma unroll
    for (int j = 0; j < 4; ++j)
#pragma unroll
      for (int r = 0; r < 4; ++r)
        epi_store<N, EPI>(m0 + wm * 128 + i * 16 + lr4 + r, n0 + wn * 64 + j * 16 + lr,
                          acc[i][j][r], outp, bias, out2);
}

// ---------- mega-fused: kv-proj + windowed attention + out-proj ----------
// grid 512 = (batch b, window win); 8 waves = 8 heads.
// LDS regions (time-shared):
//   W_ (64KB): Wkv k-tile -> V^T[head][d][key] -> Wproj k-tile
//   Br (64KB): K[head][key][d] -> P[head][q][key] -> O_all[q][512]
//   Cy (32KB): y2 window rows as 4 panels [kt][64 rows][64]
__global__ __launch_bounds__(512)
void kvattn(const unsigned short* __restrict__ y2,
            const unsigned short* __restrict__ Wkv_b,
            const unsigned short* __restrict__ qwin,
            const unsigned short* __restrict__ Wproj_b,
            const float* __restrict__ bproj,
            float* __restrict__ out) {
  __shared__ unsigned short W_[32768];
  __shared__ unsigned short Br[32768];
  __shared__ unsigned short Cy[16384];

  const int tid = threadIdx.x;
  const int wv = tid >> 6;      // head
  const int lane = tid & 63;
  const int lr = lane & 15;
  const int lg = lane >> 4;
  const int r8 = lane >> 3;
  const int sl8 = lane & 7;
  const int bb = blockIdx.x >> 6;
  const int win = blockIdx.x & 63;
  const int ht = win >> 3, wt = win & 7;

  // ---- stage y2 window rows (clamped; pad rows masked later via key>=49) ----
  {
    int m = wv * 8 + r8;
    int mm = (m < 49) ? m : 48;
    int grow = bb * 3136 + (ht * 7 + mm / 7) * 56 + wt * 7 + (mm % 7);
#pragma unroll
    for (int kt = 0; kt < 4; ++kt)
      GLOAD16(y2 + (size_t)grow * 256 + kt * 64 + ((sl8 ^ (m & 7)) * 8),
              &Cy[kt * 4096 + wv * 8 * 64]);
  }

  // ---- kv GEMM: [64 rows] x [1024 n] x K=256; wave wv owns head wv's 64 cols per half ----
  f32x4 aK[4][4], aV[4][4];
#pragma unroll
  for (int i = 0; i < 4; ++i)
#pragma unroll
    for (int j = 0; j < 4; ++j) { aK[i][j] = (f32x4){0,0,0,0}; aV[i][j] = (f32x4){0,0,0,0}; }

#pragma unroll
  for (int h2 = 0; h2 < 2; ++h2) {
    for (int kt = 0; kt < 4; ++kt) {
#pragma unroll
      for (int c = 0; c < 8; ++c) {
        int nrow = c * 64 + wv * 8 + r8;
        GLOAD16(Wkv_b + (size_t)(h2 * 512 + nrow) * 256 + kt * 64 + ((sl8 ^ (nrow & 7)) * 8),
                &W_[(c * 64 + wv * 8) * 64]);
      }
      __syncthreads();
      short8 bfrg[4][2];
#pragma unroll
      for (int nf = 0; nf < 4; ++nf)
#pragma unroll
        for (int ks = 0; ks < 2; ++ks) {
          int row = wv * 64 + nf * 16 + lr;
          bfrg[nf][ks] = *(const short8*)&W_[row * 64 + (((ks * 4 + lg) ^ (row & 7)) * 8)];
        }
#pragma unroll
      for (int mf = 0; mf < 4; ++mf)
#pragma unroll
        for (int ks = 0; ks < 2; ++ks) {
          int arow = mf * 16 + lr;
          short8 af = *(const short8*)&Cy[kt * 4096 + arow * 64 + (((ks * 4 + lg) ^ (arow & 7)) * 8)];
#pragma unroll
          for (int nf = 0; nf < 4; ++nf) {
            if (h2 == 0)
              aK[mf][nf] = __builtin_amdgcn_mfma_f32_16x16x32_bf16(af, bfrg[nf][ks], aK[mf][nf], 0, 0, 0);
            else
              aV[mf][nf] = __builtin_amdgcn_mfma_f32_16x16x32_bf16(af, bfrg[nf][ks], aV[mf][nf], 0, 0, 0);
          }
        }
      __syncthreads();
    }
  }

  // ---- write K -> Br[head][key][d] (row-XOR), V^T -> W_[head][d][key] (row-XOR) ----
#pragma unroll
  for (int mf = 0; mf < 4; ++mf)
#pragma unroll
    for (int nf = 0; nf < 4; ++nf)
#pragma unroll
      for (int r = 0; r < 4; ++r) {
        int key = mf * 16 + lg * 4 + r;
        int d = nf * 16 + lr;
        Br[wv * 4096 + key * 64 + (((d >> 3) ^ (key & 7)) * 8) + (d & 7)] = f2bf(aK[mf][nf][r]);
        W_[wv * 4096 + d * 64 + (((key >> 3) ^ (d & 7)) * 8) + (key & 7)] = f2bf(aV[mf][nf][r]);
      }
  // (wave-local from here: each wave reads only its own slices)

  // ---- QK^T: q from global q_win, K from Br ----
  const unsigned short* qb = qwin + (size_t)((bb * 8 + wv) * 64 + win) * 3136;
  f32x4 aS[4][4];
#pragma unroll
  for (int i = 0; i < 4; ++i)
#pragma unroll
    for (int j = 0; j < 4; ++j) aS[i][j] = (f32x4){0,0,0,0};
#pragma unroll
  for (int mf = 0; mf < 4; ++mf)
#pragma unroll
    for (int ks = 0; ks < 2; ++ks) {
      short8 af = *(const short8*)&qb[(mf * 16 + lr) * 64 + ks * 32 + lg * 8];
#pragma unroll
      for (int nf = 0; nf < 4; ++nf) {
        int row = nf * 16 + lr;
        short8 bk = *(const short8*)&Br[wv * 4096 + row * 64 + (((ks * 4 + lg) ^ (row & 7)) * 8)];
        aS[mf][nf] = __builtin_amdgcn_mfma_f32_16x16x32_bf16(af, bk, aS[mf][nf], 0, 0, 0);
      }
    }

  // ---- softmax over keys (mask key>=49); reduce over nf + 16-lane group ----
#pragma unroll
  for (int nf = 0; nf < 4; ++nf)
    if (nf * 16 + lr >= 49) {
#pragma unroll
      for (int mf = 0; mf < 4; ++mf)
#pragma unroll
        for (int r = 0; r < 4; ++r) aS[mf][nf][r] = -1e30f;
    }
  const float cexp = 0.125f * 1.4426950408889634f;
  float mx[4][4], sm[4][4];
#pragma unroll
  for (int mf = 0; mf < 4; ++mf)
#pragma unroll
    for (int r = 0; r < 4; ++r)
      mx[mf][r] = fmaxf(fmaxf(aS[mf][0][r], aS[mf][1][r]), fmaxf(aS[mf][2][r], aS[mf][3][r]));
#pragma unroll
  for (int m = 1; m <= 8; m <<= 1)
#pragma unroll
    for (int mf = 0; mf < 4; ++mf)
#pragma unroll
      for (int r = 0; r < 4; ++r) mx[mf][r] = fmaxf(mx[mf][r], __shfl_xor(mx[mf][r], m));
#pragma unroll
  for (int mf = 0; mf < 4; ++mf)
#pragma unroll
    for (int nf = 0; nf < 4; ++nf)
#pragma unroll
      for (int r = 0; r < 4; ++r)
        aS[mf][nf][r] = exp2f((aS[mf][nf][r] - mx[mf][r]) * cexp);
#pragma unroll
  for (int mf = 0; mf < 4; ++mf)
#pragma unroll
    for (int r = 0; r < 4; ++r)
      sm[mf][r] = aS[mf][0][r] + aS[mf][1][r] + aS[mf][2][r] + aS[mf][3][r];
#pragma unroll
  for (int m = 1; m <= 8; m <<= 1)
#pragma unroll
    for (int mf = 0; mf < 4; ++mf)
#pragma unroll
      for (int r = 0; r < 4; ++r) sm[mf][r] += __shfl_xor(sm[mf][r], m);
#pragma unroll
  for (int mf = 0; mf < 4; ++mf)
#pragma unroll
    for (int r = 0; r < 4; ++r) sm[mf][r] = 1.f / sm[mf][r];

  // ---- P -> Br (own slice, overwrites own K) ----
#pragma unroll
  for (int mf = 0; mf < 4; ++mf)
#pragma unroll
    for (int nf = 0; nf < 4; ++nf)
#pragma unroll
      for (int r = 0; r < 4; ++r) {
        int q = mf * 16 + lg * 4 + r;
        int key = nf * 16 + lr;
        Br[wv * 4096 + q * 64 + (((key >> 3) ^ (q & 7)) * 8) + (key & 7)] =
            f2bf(aS[mf][nf][r] * sm[mf][r]);
      }

  // ---- PV: P (Br own) x V^T (W_ own) ----
  f32x4 aO[4][4];
#pragma unroll
  for (int i = 0; i < 4; ++i)
#pragma unroll
    for (int j = 0; j < 4; ++j) aO[i][j] = (f32x4){0,0,0,0};
#pragma unroll
  for (int mf = 0; mf < 4; ++mf)
#pragma unroll
    for (int ks = 0; ks < 2; ++ks) {
      int qrow = mf * 16 + lr;
      short8 pf = *(const short8*)&Br[wv * 4096 + qrow * 64 + (((ks * 4 + lg) ^ (qrow & 7)) * 8)];
#pragma unroll
      for (int df = 0; df < 4; ++df) {
        int drow = df * 16 + lr;
        short8 vf = *(const short8*)&W_[wv * 4096 + drow * 64 + (((ks * 4 + lg) ^ (drow & 7)) * 8)];
        aO[mf][df] = __builtin_amdgcn_mfma_f32_16x16x32_bf16(pf, vf, aO[mf][df], 0, 0, 0);
      }
    }

  // ---- O_all -> Br [64 q][512] (cross-wave region: barrier both sides) ----
  __syncthreads();
#pragma unroll
  for (int mf = 0; mf < 4; ++mf)
#pragma unroll
    for (int nf = 0; nf < 4; ++nf)
#pragma unroll
      for (int r = 0; r < 4; ++r) {
        int q = mf * 16 + lg * 4 + r;
        int slot = nf * 2 + (lr >> 3);
        Br[q * 512 + wv * 64 + ((slot ^ (q & 7)) * 8) + (lr & 7)] = f2bf(aO[mf][nf][r]);
      }
  __syncthreads();

  // ---- out-proj: O_all (Br) x Wproj (staged in W_) ----
  f32x4 aR[4][4];
#pragma unroll
  for (int i = 0; i < 4; ++i)
#pragma unroll
    for (int j = 0; j < 4; ++j) aR[i][j] = (f32x4){0,0,0,0};
  for (int kt = 0; kt < 8; ++kt) {
#pragma unroll
    for (int c = 0; c < 8; ++c) {
      int nrow = c * 64 + wv * 8 + r8;
      GLOAD16(Wproj_b + (size_t)nrow * 512 + kt * 64 + ((sl8 ^ (nrow & 7)) * 8),
              &W_[(c * 64 + wv * 8) * 64]);
    }
    __syncthreads();
#pragma unroll
    for (int mf = 0; mf < 4; ++mf)
#pragma unroll
      for (int ks = 0; ks < 2; ++ks) {
        int qrow = mf * 16 + lr;
        short8 af = *(const short8*)&Br[qrow * 512 + kt * 64 + (((ks * 4 + lg) ^ (qrow & 7)) * 8)];
#pragma unroll
        for (int nf = 0; nf < 4; ++nf) {
          int nrow = wv * 64 + nf * 16 + lr;
          short8 bf2 = *(const short8*)&W_[nrow * 64 + (((ks * 4 + lg) ^ (nrow & 7)) * 8)];
          aR[mf][nf] = __builtin_amdgcn_mfma_f32_16x16x32_bf16(af, bf2, aR[mf][nf], 0, 0, 0);
        }
      }
    __syncthreads();
  }

  // ---- epilogue: +bias, f32 store (rows q<49 only) ----
#pragma unroll
  for (int mf = 0; mf < 4; ++mf)
#pragma unroll
    for (int nf = 0; nf < 4; ++nf)
#pragma unroll
      for (int r = 0; r < 4; ++r) {
        int q = mf * 16 + lg * 4 + r;
        if (q < 49) {
          int gm = bb * 3136 + (ht * 7 + q / 7) * 56 + wt * 7 + (q % 7);
          int col = wv * 64 + nf * 16 + lr;
          out[(size_t)gm * 512 + col] = aR[mf][nf][r] + bproj[col];
        }
      }
}

// ---------- launcher ----------
extern "C" void kernel_launch(void* const* d_in, const int* in_sizes, int n_in,
                              void* d_out, int out_size, void* d_ws, size_t ws_size,
                              hipStream_t stream) {
  const float* x     = (const float*)d_in[0];
  const float* y     = (const float*)d_in[1];
  const float* Wq    = (const float*)d_in[2];
  const float* Wkv   = (const float*)d_in[3];
  const float* Wproj = (const float*)d_in[4];
  const float* bproj = (const float*)d_in[5];
  const float* Wsr   = (const float*)d_in[6];
  const float* bsr   = (const float*)d_in[7];
  const float* gn    = (const float*)d_in[8];
  const float* bn    = (const float*)d_in[9];
  float* out = (float*)d_out;

  char* ws = (char*)d_ws;
  unsigned short* Wq_b    = (unsigned short*)ws; ws += 524288;
  unsigned short* Wkv_b   = (unsigned short*)ws; ws += 524288;
  unsigned short* Wproj_b = (unsigned short*)ws; ws += 524288;
  unsigned short* Wsr_b   = (unsigned short*)ws; ws += 131072;
  unsigned short* regA    = (unsigned short*)ws; ws += 12845056; // pooled bf16 (25088x256)
  unsigned short* q_win   = (unsigned short*)ws; ws += 25690112; // q windows (+OOB slack into regC)
  unsigned short* regC    = (unsigned short*)ws; ws += 12845056; // y2 bf16 (25088x256)

  // pool y -> regA | weight converts
  cvt_pool<<<7104, 256, 0, stream>>>(y, regA, Wq, Wkv, Wproj, Wsr,
                                     Wq_b, Wkv_b, Wproj_b, Wsr_b);

  // q projection (fused f32->bf16 A-staging) -> window layout
  gemm256f<512, 512, 0><<<dim3(2, 98), 512, 0, stream>>>(x, Wq_b, q_win, nullptr, nullptr);

  // fused conv+bias+LN+GELU -> y2
  sr_gemm<<<392, 256, 0, stream>>>(regA, Wsr_b, bsr, gn, bn, regC);

  // mega-fused kv-proj + attention + out-proj -> f32 d_out
  kvattn<<<512, 512, 0, stream>>>(regC, Wkv_b, q_win, Wproj_b, bproj, out);
}

// Round 8
// 141.353 us; speedup vs baseline: 1.2753x; 1.1362x over previous
//
#include <hip/hip_runtime.h>
#include <hip/hip_bf16.h>

// ---------- common ----------
typedef __attribute__((ext_vector_type(8))) short short8;
typedef __attribute__((ext_vector_type(4))) float f32x4;
typedef __attribute__((ext_vector_type(4))) unsigned short ushort4v;

#define DI __device__ __forceinline__

DI unsigned short f2bf(float f) {
  union { float f; unsigned int u; } a; a.f = f;
  unsigned int u = a.u;
  return (unsigned short)((u + 0x7FFFu + ((u >> 16) & 1u)) >> 16);
}

#define BARRIER() do { asm volatile("" ::: "memory"); __builtin_amdgcn_s_barrier(); asm volatile("" ::: "memory"); } while (0)
#define GLOAD16(src, dst) __builtin_amdgcn_global_load_lds( \
    (const __attribute__((address_space(1))) void*)(src), \
    (__attribute__((address_space(3))) void*)(dst), 16, 0, 0)

// Problem: B=8, H1=W1=56, N1=3136, C1=512, C2=256, NH=8, HD=64, WS=7, M=25088

// ---------- merged: 2x2 avgpool(+cvt) for y | weight f32->bf16 converts ----------
__global__ __launch_bounds__(256)
void cvt_pool(const float* __restrict__ y, unsigned short* __restrict__ pooled,
              const float* __restrict__ Wq, const float* __restrict__ Wkv,
              const float* __restrict__ Wproj, const float* __restrict__ Wsr,
              unsigned short* __restrict__ Wq_b, unsigned short* __restrict__ Wkv_b,
              unsigned short* __restrict__ Wproj_b, unsigned short* __restrict__ Wsr_b) {
  int bid = blockIdx.x;
  if (bid < 6272) {
    int t = bid * 256 + threadIdx.x;
    int cv = (t & 63) * 4;
    int bp = t >> 6;
    int b = bp / 3136, p = bp % 3136;
    int hp = p / 56, wp = p % 56;
    const float* src = y + (((size_t)b * 12544) + hp * 224 + wp * 2) * 256 + cv;
    float4 a0 = *(const float4*)(src);
    float4 a1 = *(const float4*)(src + 256);
    float4 a2 = *(const float4*)(src + 28672);
    float4 a3 = *(const float4*)(src + 28672 + 256);
    float4 av;
    av.x = (a0.x + a1.x + a2.x + a3.x) * 0.25f;
    av.y = (a0.y + a1.y + a2.y + a3.y) * 0.25f;
    av.z = (a0.z + a1.z + a2.z + a3.z) * 0.25f;
    av.w = (a0.w + a1.w + a2.w + a3.w) * 0.25f;
    ushort4v o = { f2bf(av.x), f2bf(av.y), f2bf(av.z), f2bf(av.w) };
    *(ushort4v*)&pooled[(size_t)bp * 256 + cv] = o;
  } else {
    long i = (long)(bid - 6272) * 1024 + threadIdx.x * 4;
    const float* src; unsigned short* dst; long off;
    if (i < 262144L)      { src = Wq;    dst = Wq_b;    off = i; }
    else if (i < 524288L) { src = Wkv;   dst = Wkv_b;   off = i - 262144L; }
    else if (i < 786432L) { src = Wproj; dst = Wproj_b; off = i - 524288L; }
    else                  { src = Wsr;   dst = Wsr_b;   off = i - 786432L; }
    float4 v = *(const float4*)&src[off];
    ushort4v o = { f2bf(v.x), f2bf(v.y), f2bf(v.z), f2bf(v.w) };
    *(ushort4v*)&dst[off] = o;
  }
}

// ---------- fused 1x1 conv GEMM -> +bias -> LN -> GELU (swizzled LDS) ----------
__global__ __launch_bounds__(256)
void sr_gemm(const unsigned short* __restrict__ Ap, const unsigned short* __restrict__ Wsr_b,
             const float* __restrict__ bsr, const float* __restrict__ gn,
             const float* __restrict__ bn, unsigned short* __restrict__ out) {
  __shared__ unsigned short sA[64 * 64];
  __shared__ unsigned short sB[256 * 64];
  __shared__ float red[64 * 8];

  const int tid = threadIdx.x;
  const int wv = tid >> 6;
  const int lane = tid & 63;
  const int lr = lane & 15;
  const int lg = lane >> 4;
  const int lr4 = lg * 4;
  const int m0 = blockIdx.x * 64;
  const int sr8 = lane >> 3;
  const int sl8 = lane & 7;

  f32x4 acc[4][4];
#pragma unroll
  for (int i = 0; i < 4; ++i)
#pragma unroll
    for (int j = 0; j < 4; ++j) acc[i][j] = (f32x4){0.f, 0.f, 0.f, 0.f};

  for (int kt = 0; kt < 256; kt += 64) {
#pragma unroll
    for (int c = 0; c < 2; ++c) {
      int row = wv * 16 + c * 8 + sr8;
      GLOAD16(Ap + (size_t)(m0 + row) * 256 + kt + ((sl8 ^ (row & 7)) * 8),
              &sA[(wv * 16 + c * 8) * 64]);
    }
#pragma unroll
    for (int c = 0; c < 8; ++c) {
      int row = wv * 64 + c * 8 + sr8;
      GLOAD16(Wsr_b + (size_t)row * 256 + kt + ((sl8 ^ (row & 7)) * 8),
              &sB[(wv * 64 + c * 8) * 64]);
    }
    __syncthreads();
#pragma unroll
    for (int ks = 0; ks < 2; ++ks) {
      short8 af[4], bfr[4];
#pragma unroll
      for (int i = 0; i < 4; ++i)
        af[i] = *(const short8*)&sA[(i * 16 + lr) * 64 + (((ks * 4 + lg) ^ (lr & 7)) * 8)];
#pragma unroll
      for (int j = 0; j < 4; ++j)
        bfr[j] = *(const short8*)&sB[(wv * 64 + j * 16 + lr) * 64 + (((ks * 4 + lg) ^ (lr & 7)) * 8)];
#pragma unroll
      for (int i = 0; i < 4; ++i)
#pragma unroll
        for (int j = 0; j < 4; ++j)
          acc[i][j] = __builtin_amdgcn_mfma_f32_16x16x32_bf16(af[i], bfr[j], acc[i][j], 0, 0, 0);
    }
    __syncthreads();
  }

  float bsv[4], gnv[4], bnv[4];
#pragma unroll
  for (int j = 0; j < 4; ++j) {
    int col = wv * 64 + j * 16 + lr;
    bsv[j] = bsr[col]; gnv[j] = gn[col]; bnv[j] = bn[col];
  }
  float s_[4][4], q_[4][4];
#pragma unroll
  for (int i = 0; i < 4; ++i)
#pragma unroll
    for (int r = 0; r < 4; ++r) {
      float s = 0.f, q = 0.f;
#pragma unroll
      for (int j = 0; j < 4; ++j) {
        float v = acc[i][j][r] + bsv[j];
        acc[i][j][r] = v;
        s += v; q += v * v;
      }
      s_[i][r] = s; q_[i][r] = q;
    }
#pragma unroll
  for (int m = 1; m <= 8; m <<= 1)
#pragma unroll
    for (int i = 0; i < 4; ++i)
#pragma unroll
      for (int r = 0; r < 4; ++r) {
        s_[i][r] += __shfl_xor(s_[i][r], m);
        q_[i][r] += __shfl_xor(q_[i][r], m);
      }
  if (lr == 0) {
#pragma unroll
    for (int i = 0; i < 4; ++i)
#pragma unroll
      for (int r = 0; r < 4; ++r) {
        int row = i * 16 + lr4 + r;
        red[row * 8 + wv * 2 + 0] = s_[i][r];
        red[row * 8 + wv * 2 + 1] = q_[i][r];
      }
  }
  __syncthreads();
#pragma unroll
  for (int i = 0; i < 4; ++i) {
#pragma unroll
    for (int r = 0; r < 4; ++r) {
      int row = i * 16 + lr4 + r;
      float sum = red[row * 8 + 0] + red[row * 8 + 2] + red[row * 8 + 4] + red[row * 8 + 6];
      float sq  = red[row * 8 + 1] + red[row * 8 + 3] + red[row * 8 + 5] + red[row * 8 + 7];
      float mean = sum * (1.f / 256.f);
      float var = sq * (1.f / 256.f) - mean * mean;
      float rstd = rsqrtf(var + 1e-5f);
#pragma unroll
      for (int j = 0; j < 4; ++j) {
        float t = (acc[i][j][r] - mean) * rstd * gnv[j] + bnv[j];
        t = 0.5f * t * (1.f + erff(t * 0.70710678118654752f));
        out[(size_t)(m0 + row) * 256 + wv * 64 + j * 16 + lr] = f2bf(t);
      }
    }
  }
}

// ---------- q-window scatter epilogue ----------
DI void epi_q(int gm, int gc, float v, unsigned short* outp) {
  const int b = gm / 3136, pos = gm % 3136;
  const int h = pos / 56, ww = pos % 56;
  const int head = gc >> 6, d = gc & 63;
  const size_t idx = ((((size_t)(b * 8 + head)) * 64 + (h / 7) * 8 + (ww / 7)) * 49
                      + (h % 7) * 7 + (ww % 7)) * 64 + d;
  outp[idx] = f2bf(v);
}

// ---------- 256x256 GEMM, f32 A reg-staged (fused x->bf16 convert), q-proj ----------
template<int K, int N>
__global__ __launch_bounds__(512, 2)
void gemm256f(const float* __restrict__ A,
              const unsigned short* __restrict__ Bw,
              unsigned short* __restrict__ outp) {
  __shared__ unsigned short lds[65536];
  const int tid = threadIdx.x;
  const int wv = tid >> 6;
  const int lane = tid & 63;
  const int wm = wv >> 2;
  const int wn = wv & 3;
  const int m0 = blockIdx.y * 256;
  const int n0 = blockIdx.x * 256;
  const int lr = lane & 15;
  const int lg = lane >> 4;
  const int lr4 = lg * 4;
  const int srow8 = lane >> 3;
  const int sl8 = lane & 7;
  constexpr int NT = K / 64;

  f32x4 acc[8][4];
#pragma unroll
  for (int i = 0; i < 8; ++i)
#pragma unroll
    for (int j = 0; j < 4; ++j) acc[i][j] = (f32x4){0.f, 0.f, 0.f, 0.f};

  float4 fa[4][2];
  auto loadA = [&](int t1) {
    int tsrc = (t1 < NT) ? t1 : NT - 1;
#pragma unroll
    for (int rr = 0; rr < 4; ++rr) {
      int trow = rr * 64 + wv * 8 + srow8;
      const float* p = A + (size_t)(m0 + trow) * K + tsrc * 64 + sl8 * 8;
      fa[rr][0] = *(const float4*)p;
      fa[rr][1] = *(const float4*)(p + 4);
    }
    asm volatile("" ::: "memory");
  };
  auto writeA = [&](int t1) {
#pragma unroll
    for (int rr = 0; rr < 4; ++rr) {
      int trow = rr * 64 + wv * 8 + srow8;
      union { short8 s; unsigned short u[8]; } w;
      w.u[0] = f2bf(fa[rr][0].x); w.u[1] = f2bf(fa[rr][0].y);
      w.u[2] = f2bf(fa[rr][0].z); w.u[3] = f2bf(fa[rr][0].w);
      w.u[4] = f2bf(fa[rr][1].x); w.u[5] = f2bf(fa[rr][1].y);
      w.u[6] = f2bf(fa[rr][1].z); w.u[7] = f2bf(fa[rr][1].w);
      *(short8*)&lds[(t1 & 1) * 32768 + trow * 64 + ((sl8 ^ (trow & 7)) * 8)] = w.s;
    }
  };
  auto stageB = [&](int t1, int rr) {
    int tsrc = (t1 < NT) ? t1 : NT - 1;
    int trow = rr * 64 + wv * 8 + srow8;
    int sx = sl8 ^ (trow & 7);
    GLOAD16(Bw + (size_t)(n0 + trow) * K + tsrc * 64 + sx * 8,
            &lds[(t1 & 1) * 32768 + 16384 + (rr * 64 + wv * 8) * 64]);
  };
  auto rdA = [&](int s, int mf, int ks) -> short8 {
    int row = wm * 128 + mf * 16 + lr;
    int slot = ((ks << 2) + lg) ^ (row & 7);
    return *(const short8*)&lds[s * 32768 + row * 64 + slot * 8];
  };
  auto rdB = [&](int s, int nf, int ks) -> short8 {
    int row = wn * 64 + nf * 16 + lr;
    int slot = ((ks << 2) + lg) ^ (row & 7);
    return *(const short8*)&lds[s * 32768 + 16384 + row * 64 + slot * 8];
  };

  stageB(0, 0); stageB(0, 1); stageB(0, 2); stageB(0, 3);
  loadA(0);
  asm volatile("s_waitcnt vmcnt(0)" ::: "memory");
  writeA(0);
  asm volatile("s_waitcnt lgkmcnt(0)" ::: "memory");
  BARRIER();

  for (int t = 0; t < NT; ++t) {
    const int s = t & 1;
    short8 bfr[4][2];
    loadA(t + 1);
#pragma unroll
    for (int j = 0; j < 4; ++j) { bfr[j][0] = rdB(s, j, 0); bfr[j][1] = rdB(s, j, 1); }
    {
      short8 x0 = rdA(s, 0, 0), x1 = rdA(s, 0, 1);
      short8 y0 = rdA(s, 1, 0), y1 = rdA(s, 1, 1);
      BARRIER();
      __builtin_amdgcn_s_setprio(1);
#pragma unroll
      for (int j = 0; j < 4; ++j) {
        acc[0][j] = __builtin_amdgcn_mfma_f32_16x16x32_bf16(x0, bfr[j][0], acc[0][j], 0, 0, 0);
        acc[0][j] = __builtin_amdgcn_mfma_f32_16x16x32_bf16(x1, bfr[j][1], acc[0][j], 0, 0, 0);
        acc[1][j] = __builtin_amdgcn_mfma_f32_16x16x32_bf16(y0, bfr[j][0], acc[1][j], 0, 0, 0);
        acc[1][j] = __builtin_amdgcn_mfma_f32_16x16x32_bf16(y1, bfr[j][1], acc[1][j], 0, 0, 0);
      }
      __builtin_amdgcn_s_setprio(0);
      BARRIER();
    }
    stageB(t + 1, 0); stageB(t + 1, 1);
    {
      short8 x0 = rdA(s, 2, 0), x1 = rdA(s, 2, 1);
      short8 y0 = rdA(s, 3, 0), y1 = rdA(s, 3, 1);
      BARRIER();
      __builtin_amdgcn_s_setprio(1);
#pragma unroll
      for (int j = 0; j < 4; ++j) {
        acc[2][j] = __builtin_amdgcn_mfma_f32_16x16x32_bf16(x0, bfr[j][0], acc[2][j], 0, 0, 0);
        acc[2][j] = __builtin_amdgcn_mfma_f32_16x16x32_bf16(x1, bfr[j][1], acc[2][j], 0, 0, 0);
        acc[3][j] = __builtin_amdgcn_mfma_f32_16x16x32_bf16(y0, bfr[j][0], acc[3][j], 0, 0, 0);
        acc[3][j] = __builtin_amdgcn_mfma_f32_16x16x32_bf16(y1, bfr[j][1], acc[3][j], 0, 0, 0);
      }
      __builtin_amdgcn_s_setprio(0);
      BARRIER();
    }
    stageB(t + 1, 2); stageB(t + 1, 3);
    {
      short8 x0 = rdA(s, 4, 0), x1 = rdA(s, 4, 1);
      short8 y0 = rdA(s, 5, 0), y1 = rdA(s, 5, 1);
      BARRIER();
      __builtin_amdgcn_s_setprio(1);
#pragma unroll
      for (int j = 0; j < 4; ++j) {
        acc[4][j] = __builtin_amdgcn_mfma_f32_16x16x32_bf16(x0, bfr[j][0], acc[4][j], 0, 0, 0);
        acc[4][j] = __builtin_amdgcn_mfma_f32_16x16x32_bf16(x1, bfr[j][1], acc[4][j], 0, 0, 0);
        acc[5][j] = __builtin_amdgcn_mfma_f32_16x16x32_bf16(y0, bfr[j][0], acc[5][j], 0, 0, 0);
        acc[5][j] = __builtin_amdgcn_mfma_f32_16x16x32_bf16(y1, bfr[j][1], acc[5][j], 0, 0, 0);
      }
      __builtin_amdgcn_s_setprio(0);
      BARRIER();
    }
    {
      short8 x0 = rdA(s, 6, 0), x1 = rdA(s, 6, 1);
      short8 y0 = rdA(s, 7, 0), y1 = rdA(s, 7, 1);
      asm volatile("s_waitcnt vmcnt(4)" ::: "memory");
      writeA(t + 1);
      asm volatile("s_waitcnt lgkmcnt(0)" ::: "memory");
      BARRIER();
      __builtin_amdgcn_s_setprio(1);
#pragma unroll
      for (int j = 0; j < 4; ++j) {
        acc[6][j] = __builtin_amdgcn_mfma_f32_16x16x32_bf16(x0, bfr[j][0], acc[6][j], 0, 0, 0);
        acc[6][j] = __builtin_amdgcn_mfma_f32_16x16x32_bf16(x1, bfr[j][1], acc[6][j], 0, 0, 0);
        acc[7][j] = __builtin_amdgcn_mfma_f32_16x16x32_bf16(y0, bfr[j][0], acc[7][j], 0, 0, 0);
        acc[7][j] = __builtin_amdgcn_mfma_f32_16x16x32_bf16(y1, bfr[j][1], acc[7][j], 0, 0, 0);
      }
      __builtin_amdgcn_s_setprio(0);
      asm volatile("s_waitcnt vmcnt(0)" ::: "memory");
      BARRIER();
    }
  }

#pragma unroll
  for (int i = 0; i < 8; ++i)
#pragma unroll
    for (int j = 0; j < 4; ++j)
#pragma unroll
      for (int r = 0; r < 4; ++r)
        epi_q(m0 + wm * 128 + i * 16 + lr4 + r, n0 + wn * 64 + j * 16 + lr,
              acc[i][j][r], outp);
}

// ---------- mega-fused kv-proj + attention + out-proj, per-wave pipelined ----------
// grid 512 = (b, win); 8 waves = 8 heads. 3 barriers total.
// LDS 160KB: Cy [0,32K) | per-wave 16K slice [32K+wv*16K) | OA [32K,96K) | WP [96K+wv*8K)
__global__ __launch_bounds__(512)
void kvattn(const unsigned short* __restrict__ y2,
            const unsigned short* __restrict__ Wkv_b,
            const unsigned short* __restrict__ qwin,
            const unsigned short* __restrict__ Wproj_b,
            const float* __restrict__ bproj,
            float* __restrict__ out) {
  __shared__ unsigned short lds[81920];
  const int tid = threadIdx.x;
  const int wv = tid >> 6;
  const int lane = tid & 63;
  const int lr = lane & 15;
  const int lg = lane >> 4;
  const int r8 = lane >> 3;
  const int sl8 = lane & 7;
  const int bb = blockIdx.x >> 6;
  const int win = blockIdx.x & 63;
  const int ht = win >> 3, wt = win & 7;

  unsigned short* Cy = lds;                      // [kt][64][64], shared
  unsigned short* SL = lds + 16384 + wv * 8192;  // per-wave: buf0 +0, buf1 +4096
  unsigned short* OA = lds + 16384;              // [64][512], time-shared
  unsigned short* WP = lds + 49152 + wv * 4096;  // per-wave Wproj tile

  // ---- Cy: y2 window rows (clamped; pad keys masked in softmax) ----
  {
    int m = wv * 8 + r8;
    int mm = (m < 49) ? m : 48;
    int grow = bb * 3136 + (ht * 7 + mm / 7) * 56 + wt * 7 + (mm % 7);
#pragma unroll
    for (int kt = 0; kt < 4; ++kt)
      GLOAD16(y2 + (size_t)grow * 256 + kt * 64 + ((sl8 ^ (m & 7)) * 8),
              &Cy[kt * 4096 + wv * 8 * 64]);
  }

  // ---- per-wave Wkv staging (own head's rows only; no barriers) ----
  auto stageW = [&](int s) {  // s: h2 = s>>2, kt = s&3
    int h2 = s >> 2, kt = s & 3;
#pragma unroll
    for (int c = 0; c < 8; ++c) {
      int lrow = c * 8 + r8;
      GLOAD16(Wkv_b + (size_t)(h2 * 512 + wv * 64 + lrow) * 256 + kt * 64 + ((sl8 ^ (lrow & 7)) * 8),
              &SL[(s & 1) * 4096 + c * 8 * 64]);
    }
  };

  f32x4 aK[4][4], aV[4][4];
#pragma unroll
  for (int i = 0; i < 4; ++i)
#pragma unroll
    for (int j = 0; j < 4; ++j) { aK[i][j] = (f32x4){0,0,0,0}; aV[i][j] = (f32x4){0,0,0,0}; }

  stageW(0);
  asm volatile("s_waitcnt vmcnt(8)" ::: "memory");  // Cy's 4 retired (stage0's 8 in flight)
  BARRIER();                                        // Cy visible to all waves

#pragma unroll
  for (int s = 0; s < 8; ++s) {
    if (s < 7) {
      stageW(s + 1);
      asm volatile("s_waitcnt vmcnt(8)" ::: "memory");  // retire stage s
    } else {
      asm volatile("s_waitcnt vmcnt(0)" ::: "memory");
    }
    const int kt = s & 3;
    const unsigned short* Wb = &SL[(s & 1) * 4096];
    short8 bfrg[4][2];
#pragma unroll
    for (int nf = 0; nf < 4; ++nf)
#pragma unroll
      for (int ks = 0; ks < 2; ++ks)
        bfrg[nf][ks] = *(const short8*)&Wb[(nf * 16 + lr) * 64 + (((ks * 4 + lg) ^ (lr & 7)) * 8)];
#pragma unroll
    for (int mf = 0; mf < 4; ++mf)
#pragma unroll
      for (int ks = 0; ks < 2; ++ks) {
        short8 af = *(const short8*)&Cy[kt * 4096 + (mf * 16 + lr) * 64 + (((ks * 4 + lg) ^ (lr & 7)) * 8)];
#pragma unroll
        for (int nf = 0; nf < 4; ++nf) {
          if (s < 4)
            aK[mf][nf] = __builtin_amdgcn_mfma_f32_16x16x32_bf16(af, bfrg[nf][ks], aK[mf][nf], 0, 0, 0);
          else
            aV[mf][nf] = __builtin_amdgcn_mfma_f32_16x16x32_bf16(af, bfrg[nf][ks], aV[mf][nf], 0, 0, 0);
        }
      }
  }

  // ---- q fragments from global (overlaps with following LDS writes) ----
  const unsigned short* qb = qwin + (size_t)((bb * 8 + wv) * 64 + win) * 3136;
  short8 qf[4][2];
#pragma unroll
  for (int mf = 0; mf < 4; ++mf)
#pragma unroll
    for (int ks = 0; ks < 2; ++ks)
      qf[mf][ks] = *(const short8*)&qb[(mf * 16 + lr) * 64 + ks * 32 + lg * 8];

  // ---- K -> SL buf0 [key][d], V^T -> SL buf1 [d][key] (own slice; wave-local) ----
#pragma unroll
  for (int mf = 0; mf < 4; ++mf)
#pragma unroll
    for (int nf = 0; nf < 4; ++nf)
#pragma unroll
      for (int r = 0; r < 4; ++r) {
        int key = mf * 16 + lg * 4 + r;
        int d = nf * 16 + lr;
        SL[key * 64 + (((d >> 3) ^ (key & 7)) * 8) + (d & 7)] = f2bf(aK[mf][nf][r]);
        SL[4096 + d * 64 + (((key >> 3) ^ (d & 7)) * 8) + (key & 7)] = f2bf(aV[mf][nf][r]);
      }

  // ---- QK^T (wave-local) ----
  f32x4 aS[4][4];
#pragma unroll
  for (int i = 0; i < 4; ++i)
#pragma unroll
    for (int j = 0; j < 4; ++j) aS[i][j] = (f32x4){0,0,0,0};
#pragma unroll
  for (int mf = 0; mf < 4; ++mf)
#pragma unroll
    for (int ks = 0; ks < 2; ++ks)
#pragma unroll
      for (int nf = 0; nf < 4; ++nf) {
        short8 bk = *(const short8*)&SL[(nf * 16 + lr) * 64 + (((ks * 4 + lg) ^ (lr & 7)) * 8)];
        aS[mf][nf] = __builtin_amdgcn_mfma_f32_16x16x32_bf16(qf[mf][ks], bk, aS[mf][nf], 0, 0, 0);
      }

  // ---- softmax over keys (mask >=49) ----
#pragma unroll
  for (int nf = 0; nf < 4; ++nf)
    if (nf * 16 + lr >= 49) {
#pragma unroll
      for (int mf = 0; mf < 4; ++mf)
#pragma unroll
        for (int r = 0; r < 4; ++r) aS[mf][nf][r] = -1e30f;
    }
  const float cexp = 0.125f * 1.4426950408889634f;
  float mx[4][4], sm[4][4];
#pragma unroll
  for (int mf = 0; mf < 4; ++mf)
#pragma unroll
    for (int r = 0; r < 4; ++r)
      mx[mf][r] = fmaxf(fmaxf(aS[mf][0][r], aS[mf][1][r]), fmaxf(aS[mf][2][r], aS[mf][3][r]));
#pragma unroll
  for (int m = 1; m <= 8; m <<= 1)
#pragma unroll
    for (int mf = 0; mf < 4; ++mf)
#pragma unroll
      for (int r = 0; r < 4; ++r) mx[mf][r] = fmaxf(mx[mf][r], __shfl_xor(mx[mf][r], m));
#pragma unroll
  for (int mf = 0; mf < 4; ++mf)
#pragma unroll
    for (int nf = 0; nf < 4; ++nf)
#pragma unroll
      for (int r = 0; r < 4; ++r)
        aS[mf][nf][r] = exp2f((aS[mf][nf][r] - mx[mf][r]) * cexp);
#pragma unroll
  for (int mf = 0; mf < 4; ++mf)
#pragma unroll
    for (int r = 0; r < 4; ++r)
      sm[mf][r] = aS[mf][0][r] + aS[mf][1][r] + aS[mf][2][r] + aS[mf][3][r];
#pragma unroll
  for (int m = 1; m <= 8; m <<= 1)
#pragma unroll
    for (int mf = 0; mf < 4; ++mf)
#pragma unroll
      for (int r = 0; r < 4; ++r) sm[mf][r] += __shfl_xor(sm[mf][r], m);
#pragma unroll
  for (int mf = 0; mf < 4; ++mf)
#pragma unroll
    for (int r = 0; r < 4; ++r) sm[mf][r] = 1.f / sm[mf][r];

  // ---- P -> SL buf0 (overwrites K; wave-local) ----
#pragma unroll
  for (int mf = 0; mf < 4; ++mf)
#pragma unroll
    for (int nf = 0; nf < 4; ++nf)
#pragma unroll
      for (int r = 0; r < 4; ++r) {
        int q = mf * 16 + lg * 4 + r;
        int key = nf * 16 + lr;
        SL[q * 64 + (((key >> 3) ^ (q & 7)) * 8) + (key & 7)] = f2bf(aS[mf][nf][r] * sm[mf][r]);
      }

  // ---- PV (wave-local) ----
  f32x4 aO[4][4];
#pragma unroll
  for (int i = 0; i < 4; ++i)
#pragma unroll
    for (int j = 0; j < 4; ++j) aO[i][j] = (f32x4){0,0,0,0};
#pragma unroll
  for (int mf = 0; mf < 4; ++mf)
#pragma unroll
    for (int ks = 0; ks < 2; ++ks) {
      short8 pf = *(const short8*)&SL[(mf * 16 + lr) * 64 + (((ks * 4 + lg) ^ (lr & 7)) * 8)];
#pragma unroll
      for (int df = 0; df < 4; ++df) {
        short8 vf = *(const short8*)&SL[4096 + (df * 16 + lr) * 64 + (((ks * 4 + lg) ^ (lr & 7)) * 8)];
        aO[mf][df] = __builtin_amdgcn_mfma_f32_16x16x32_bf16(pf, vf, aO[mf][df], 0, 0, 0);
      }
    }

  // ---- O_all + first Wproj tile ----
  BARRIER();   // all waves past PV; SL region reusable
#pragma unroll
  for (int mf = 0; mf < 4; ++mf)
#pragma unroll
    for (int nf = 0; nf < 4; ++nf)
#pragma unroll
      for (int r = 0; r < 4; ++r) {
        int q = mf * 16 + lg * 4 + r;
        int slot = nf * 2 + (lr >> 3);
        OA[q * 512 + wv * 64 + ((slot ^ (q & 7)) * 8) + (lr & 7)] = f2bf(aO[mf][nf][r]);
      }
  {
    short8 nx[8];
#pragma unroll
    for (int c = 0; c < 8; ++c) {
      int lrow = c * 8 + r8;
      nx[c] = *(const short8*)&Wproj_b[(size_t)(wv * 64 + lrow) * 512 + ((sl8 ^ (lrow & 7)) * 8)];
    }
#pragma unroll
    for (int c = 0; c < 8; ++c)
      *(short8*)&WP[(c * 8 + r8) * 64 + sl8 * 8] = nx[c];
  }
  BARRIER();   // OA + WP(0) visible / ordered

  // ---- out-proj: per-wave reg-prefetched Wproj pipeline ----
  f32x4 aR[4][4];
#pragma unroll
  for (int i = 0; i < 4; ++i)
#pragma unroll
    for (int j = 0; j < 4; ++j) aR[i][j] = (f32x4){0,0,0,0};
#pragma unroll
  for (int kt = 0; kt < 8; ++kt) {
    short8 nx[8];
    if (kt < 7) {
#pragma unroll
      for (int c = 0; c < 8; ++c) {
        int lrow = c * 8 + r8;
        nx[c] = *(const short8*)&Wproj_b[(size_t)(wv * 64 + lrow) * 512 + (kt + 1) * 64 + ((sl8 ^ (lrow & 7)) * 8)];
      }
    }
#pragma unroll
    for (int mf = 0; mf < 4; ++mf)
#pragma unroll
      for (int ks = 0; ks < 2; ++ks) {
        short8 af = *(const short8*)&OA[(mf * 16 + lr) * 512 + kt * 64 + (((ks * 4 + lg) ^ (lr & 7)) * 8)];
#pragma unroll
        for (int nf = 0; nf < 4; ++nf) {
          short8 bf2 = *(const short8*)&WP[(nf * 16 + lr) * 64 + (((ks * 4 + lg) ^ (lr & 7)) * 8)];
          aR[mf][nf] = __builtin_amdgcn_mfma_f32_16x16x32_bf16(af, bf2, aR[mf][nf], 0, 0, 0);
        }
      }
    if (kt < 7) {
#pragma unroll
      for (int c = 0; c < 8; ++c)
        *(short8*)&WP[(c * 8 + r8) * 64 + sl8 * 8] = nx[c];
    }
  }

  // ---- epilogue: +bias, f32 store (q<49) ----
#pragma unroll
  for (int mf = 0; mf < 4; ++mf)
#pragma unroll
    for (int nf = 0; nf < 4; ++nf)
#pragma unroll
      for (int r = 0; r < 4; ++r) {
        int q = mf * 16 + lg * 4 + r;
        if (q < 49) {
          int gm = bb * 3136 + (ht * 7 + q / 7) * 56 + wt * 7 + (q % 7);
          int col = wv * 64 + nf * 16 + lr;
          out[(size_t)gm * 512 + col] = aR[mf][nf][r] + bproj[col];
        }
      }
}

// ---------- launcher ----------
extern "C" void kernel_launch(void* const* d_in, const int* in_sizes, int n_in,
                              void* d_out, int out_size, void* d_ws, size_t ws_size,
                              hipStream_t stream) {
  const float* x     = (const float*)d_in[0];
  const float* y     = (const float*)d_in[1];
  const float* Wq    = (const float*)d_in[2];
  const float* Wkv   = (const float*)d_in[3];
  const float* Wproj = (const float*)d_in[4];
  const float* bproj = (const float*)d_in[5];
  const float* Wsr   = (const float*)d_in[6];
  const float* bsr   = (const float*)d_in[7];
  const float* gn    = (const float*)d_in[8];
  const float* bn    = (const float*)d_in[9];
  float* out = (float*)d_out;

  char* ws = (char*)d_ws;
  unsigned short* Wq_b    = (unsigned short*)ws; ws += 524288;
  unsigned short* Wkv_b   = (unsigned short*)ws; ws += 524288;
  unsigned short* Wproj_b = (unsigned short*)ws; ws += 524288;
  unsigned short* Wsr_b   = (unsigned short*)ws; ws += 131072;
  unsigned short* regA    = (unsigned short*)ws; ws += 12845056; // pooled bf16
  unsigned short* q_win   = (unsigned short*)ws; ws += 25690112; // q windows
  unsigned short* regC    = (unsigned short*)ws; ws += 12845056; // y2 bf16

  // pool y -> regA | weight converts
  cvt_pool<<<7104, 256, 0, stream>>>(y, regA, Wq, Wkv, Wproj, Wsr,
                                     Wq_b, Wkv_b, Wproj_b, Wsr_b);

  // q projection (fused f32->bf16 A-staging) -> window layout
  gemm256f<512, 512><<<dim3(2, 98), 512, 0, stream>>>(x, Wq_b, q_win);

  // fused conv+bias+LN+GELU -> y2
  sr_gemm<<<392, 256, 0, stream>>>(regA, Wsr_b, bsr, gn, bn, regC);

  // mega-fused kv-proj + attention + out-proj -> f32 d_out
  kvattn<<<512, 512, 0, stream>>>(regC, Wkv_b, q_win, Wproj_b, bproj, out);
}

// Round 9
// 139.831 us; speedup vs baseline: 1.2892x; 1.0109x over previous
//
#include <hip/hip_runtime.h>
#include <hip/hip_bf16.h>

// ---------- common ----------
typedef __attribute__((ext_vector_type(8))) short short8;
typedef __attribute__((ext_vector_type(4))) float f32x4;
typedef __attribute__((ext_vector_type(4))) unsigned short ushort4v;

#define DI __device__ __forceinline__

DI unsigned short f2bf(float f) {
  union { float f; unsigned int u; } a; a.f = f;
  unsigned int u = a.u;
  return (unsigned short)((u + 0x7FFFu + ((u >> 16) & 1u)) >> 16);
}

#define BARRIER() do { asm volatile("" ::: "memory"); __builtin_amdgcn_s_barrier(); asm volatile("" ::: "memory"); } while (0)
#define GLOAD16(src, dst) __builtin_amdgcn_global_load_lds( \
    (const __attribute__((address_space(1))) void*)(src), \
    (__attribute__((address_space(3))) void*)(dst), 16, 0, 0)

// Problem: B=8, H1=W1=56, N1=3136, C1=512, C2=256, NH=8, HD=64, WS=7, M=25088

// ---------- merged: 2x2 avgpool(+cvt) for y | weight f32->bf16 converts ----------
__global__ __launch_bounds__(256)
void cvt_pool(const float* __restrict__ y, unsigned short* __restrict__ pooled,
              const float* __restrict__ Wq, const float* __restrict__ Wkv,
              const float* __restrict__ Wproj, const float* __restrict__ Wsr,
              unsigned short* __restrict__ Wq_b, unsigned short* __restrict__ Wkv_b,
              unsigned short* __restrict__ Wproj_b, unsigned short* __restrict__ Wsr_b) {
  int bid = blockIdx.x;
  if (bid < 6272) {
    int t = bid * 256 + threadIdx.x;
    int cv = (t & 63) * 4;
    int bp = t >> 6;
    int b = bp / 3136, p = bp % 3136;
    int hp = p / 56, wp = p % 56;
    const float* src = y + (((size_t)b * 12544) + hp * 224 + wp * 2) * 256 + cv;
    float4 a0 = *(const float4*)(src);
    float4 a1 = *(const float4*)(src + 256);
    float4 a2 = *(const float4*)(src + 28672);
    float4 a3 = *(const float4*)(src + 28672 + 256);
    float4 av;
    av.x = (a0.x + a1.x + a2.x + a3.x) * 0.25f;
    av.y = (a0.y + a1.y + a2.y + a3.y) * 0.25f;
    av.z = (a0.z + a1.z + a2.z + a3.z) * 0.25f;
    av.w = (a0.w + a1.w + a2.w + a3.w) * 0.25f;
    ushort4v o = { f2bf(av.x), f2bf(av.y), f2bf(av.z), f2bf(av.w) };
    *(ushort4v*)&pooled[(size_t)bp * 256 + cv] = o;
  } else {
    long i = (long)(bid - 6272) * 1024 + threadIdx.x * 4;
    const float* src; unsigned short* dst; long off;
    if (i < 262144L)      { src = Wq;    dst = Wq_b;    off = i; }
    else if (i < 524288L) { src = Wkv;   dst = Wkv_b;   off = i - 262144L; }
    else if (i < 786432L) { src = Wproj; dst = Wproj_b; off = i - 524288L; }
    else                  { src = Wsr;   dst = Wsr_b;   off = i - 786432L; }
    float4 v = *(const float4*)&src[off];
    ushort4v o = { f2bf(v.x), f2bf(v.y), f2bf(v.z), f2bf(v.w) };
    *(ushort4v*)&dst[off] = o;
  }
}

// ---------- fused 1x1 conv GEMM -> +bias -> LN -> GELU (swizzled LDS) ----------
__global__ __launch_bounds__(256)
void sr_gemm(const unsigned short* __restrict__ Ap, const unsigned short* __restrict__ Wsr_b,
             const float* __restrict__ bsr, const float* __restrict__ gn,
             const float* __restrict__ bn, unsigned short* __restrict__ out) {
  __shared__ unsigned short sA[64 * 64];
  __shared__ unsigned short sB[256 * 64];
  __shared__ float red[64 * 8];

  const int tid = threadIdx.x;
  const int wv = tid >> 6;
  const int lane = tid & 63;
  const int lr = lane & 15;
  const int lg = lane >> 4;
  const int lr4 = lg * 4;
  const int m0 = blockIdx.x * 64;
  const int sr8 = lane >> 3;
  const int sl8 = lane & 7;

  f32x4 acc[4][4];
#pragma unroll
  for (int i = 0; i < 4; ++i)
#pragma unroll
    for (int j = 0; j < 4; ++j) acc[i][j] = (f32x4){0.f, 0.f, 0.f, 0.f};

  for (int kt = 0; kt < 256; kt += 64) {
#pragma unroll
    for (int c = 0; c < 2; ++c) {
      int row = wv * 16 + c * 8 + sr8;
      GLOAD16(Ap + (size_t)(m0 + row) * 256 + kt + ((sl8 ^ (row & 7)) * 8),
              &sA[(wv * 16 + c * 8) * 64]);
    }
#pragma unroll
    for (int c = 0; c < 8; ++c) {
      int row = wv * 64 + c * 8 + sr8;
      GLOAD16(Wsr_b + (size_t)row * 256 + kt + ((sl8 ^ (row & 7)) * 8),
              &sB[(wv * 64 + c * 8) * 64]);
    }
    __syncthreads();
#pragma unroll
    for (int ks = 0; ks < 2; ++ks) {
      short8 af[4], bfr[4];
#pragma unroll
      for (int i = 0; i < 4; ++i)
        af[i] = *(const short8*)&sA[(i * 16 + lr) * 64 + (((ks * 4 + lg) ^ (lr & 7)) * 8)];
#pragma unroll
      for (int j = 0; j < 4; ++j)
        bfr[j] = *(const short8*)&sB[(wv * 64 + j * 16 + lr) * 64 + (((ks * 4 + lg) ^ (lr & 7)) * 8)];
#pragma unroll
      for (int i = 0; i < 4; ++i)
#pragma unroll
        for (int j = 0; j < 4; ++j)
          acc[i][j] = __builtin_amdgcn_mfma_f32_16x16x32_bf16(af[i], bfr[j], acc[i][j], 0, 0, 0);
    }
    __syncthreads();
  }

  float bsv[4], gnv[4], bnv[4];
#pragma unroll
  for (int j = 0; j < 4; ++j) {
    int col = wv * 64 + j * 16 + lr;
    bsv[j] = bsr[col]; gnv[j] = gn[col]; bnv[j] = bn[col];
  }
  float s_[4][4], q_[4][4];
#pragma unroll
  for (int i = 0; i < 4; ++i)
#pragma unroll
    for (int r = 0; r < 4; ++r) {
      float s = 0.f, q = 0.f;
#pragma unroll
      for (int j = 0; j < 4; ++j) {
        float v = acc[i][j][r] + bsv[j];
        acc[i][j][r] = v;
        s += v; q += v * v;
      }
      s_[i][r] = s; q_[i][r] = q;
    }
#pragma unroll
  for (int m = 1; m <= 8; m <<= 1)
#pragma unroll
    for (int i = 0; i < 4; ++i)
#pragma unroll
      for (int r = 0; r < 4; ++r) {
        s_[i][r] += __shfl_xor(s_[i][r], m);
        q_[i][r] += __shfl_xor(q_[i][r], m);
      }
  if (lr == 0) {
#pragma unroll
    for (int i = 0; i < 4; ++i)
#pragma unroll
      for (int r = 0; r < 4; ++r) {
        int row = i * 16 + lr4 + r;
        red[row * 8 + wv * 2 + 0] = s_[i][r];
        red[row * 8 + wv * 2 + 1] = q_[i][r];
      }
  }
  __syncthreads();
#pragma unroll
  for (int i = 0; i < 4; ++i) {
#pragma unroll
    for (int r = 0; r < 4; ++r) {
      int row = i * 16 + lr4 + r;
      float sum = red[row * 8 + 0] + red[row * 8 + 2] + red[row * 8 + 4] + red[row * 8 + 6];
      float sq  = red[row * 8 + 1] + red[row * 8 + 3] + red[row * 8 + 5] + red[row * 8 + 7];
      float mean = sum * (1.f / 256.f);
      float var = sq * (1.f / 256.f) - mean * mean;
      float rstd = rsqrtf(var + 1e-5f);
#pragma unroll
      for (int j = 0; j < 4; ++j) {
        float t = (acc[i][j][r] - mean) * rstd * gnv[j] + bnv[j];
        t = 0.5f * t * (1.f + erff(t * 0.70710678118654752f));
        out[(size_t)(m0 + row) * 256 + wv * 64 + j * 16 + lr] = f2bf(t);
      }
    }
  }
}

// ---------- q-window scatter epilogue ----------
DI void epi_q(int gm, int gc, float v, unsigned short* outp) {
  const int b = gm / 3136, pos = gm % 3136;
  const int h = pos / 56, ww = pos % 56;
  const int head = gc >> 6, d = gc & 63;
  const size_t idx = ((((size_t)(b * 8 + head)) * 64 + (h / 7) * 8 + (ww / 7)) * 49
                      + (h % 7) * 7 + (ww % 7)) * 64 + d;
  outp[idx] = f2bf(v);
}

// ---------- 256x256 GEMM, f32 A reg-staged (fused x->bf16 convert), q-proj ----------
template<int K, int N>
__global__ __launch_bounds__(512, 2)
void gemm256f(const float* __restrict__ A,
              const unsigned short* __restrict__ Bw,
              unsigned short* __restrict__ outp) {
  __shared__ unsigned short lds[65536];
  const int tid = threadIdx.x;
  const int wv = tid >> 6;
  const int lane = tid & 63;
  const int wm = wv >> 2;
  const int wn = wv & 3;
  const int m0 = blockIdx.y * 256;
  const int n0 = blockIdx.x * 256;
  const int lr = lane & 15;
  const int lg = lane >> 4;
  const int lr4 = lg * 4;
  const int srow8 = lane >> 3;
  const int sl8 = lane & 7;
  constexpr int NT = K / 64;

  f32x4 acc[8][4];
#pragma unroll
  for (int i = 0; i < 8; ++i)
#pragma unroll
    for (int j = 0; j < 4; ++j) acc[i][j] = (f32x4){0.f, 0.f, 0.f, 0.f};

  float4 fa[4][2];
  auto loadA = [&](int t1) {
    int tsrc = (t1 < NT) ? t1 : NT - 1;
#pragma unroll
    for (int rr = 0; rr < 4; ++rr) {
      int trow = rr * 64 + wv * 8 + srow8;
      const float* p = A + (size_t)(m0 + trow) * K + tsrc * 64 + sl8 * 8;
      fa[rr][0] = *(const float4*)p;
      fa[rr][1] = *(const float4*)(p + 4);
    }
    asm volatile("" ::: "memory");
  };
  auto writeA = [&](int t1) {
#pragma unroll
    for (int rr = 0; rr < 4; ++rr) {
      int trow = rr * 64 + wv * 8 + srow8;
      union { short8 s; unsigned short u[8]; } w;
      w.u[0] = f2bf(fa[rr][0].x); w.u[1] = f2bf(fa[rr][0].y);
      w.u[2] = f2bf(fa[rr][0].z); w.u[3] = f2bf(fa[rr][0].w);
      w.u[4] = f2bf(fa[rr][1].x); w.u[5] = f2bf(fa[rr][1].y);
      w.u[6] = f2bf(fa[rr][1].z); w.u[7] = f2bf(fa[rr][1].w);
      *(short8*)&lds[(t1 & 1) * 32768 + trow * 64 + ((sl8 ^ (trow & 7)) * 8)] = w.s;
    }
  };
  auto stageB = [&](int t1, int rr) {
    int tsrc = (t1 < NT) ? t1 : NT - 1;
    int trow = rr * 64 + wv * 8 + srow8;
    int sx = sl8 ^ (trow & 7);
    GLOAD16(Bw + (size_t)(n0 + trow) * K + tsrc * 64 + sx * 8,
            &lds[(t1 & 1) * 32768 + 16384 + (rr * 64 + wv * 8) * 64]);
  };
  auto rdA = [&](int s, int mf, int ks) -> short8 {
    int row = wm * 128 + mf * 16 + lr;
    int slot = ((ks << 2) + lg) ^ (row & 7);
    return *(const short8*)&lds[s * 32768 + row * 64 + slot * 8];
  };
  auto rdB = [&](int s, int nf, int ks) -> short8 {
    int row = wn * 64 + nf * 16 + lr;
    int slot = ((ks << 2) + lg) ^ (row & 7);
    return *(const short8*)&lds[s * 32768 + 16384 + row * 64 + slot * 8];
  };

  stageB(0, 0); stageB(0, 1); stageB(0, 2); stageB(0, 3);
  loadA(0);
  asm volatile("s_waitcnt vmcnt(0)" ::: "memory");
  writeA(0);
  asm volatile("s_waitcnt lgkmcnt(0)" ::: "memory");
  BARRIER();

  for (int t = 0; t < NT; ++t) {
    const int s = t & 1;
    short8 bfr[4][2];
    loadA(t + 1);
#pragma unroll
    for (int j = 0; j < 4; ++j) { bfr[j][0] = rdB(s, j, 0); bfr[j][1] = rdB(s, j, 1); }
    {
      short8 x0 = rdA(s, 0, 0), x1 = rdA(s, 0, 1);
      short8 y0 = rdA(s, 1, 0), y1 = rdA(s, 1, 1);
      BARRIER();
      __builtin_amdgcn_s_setprio(1);
#pragma unroll
      for (int j = 0; j < 4; ++j) {
        acc[0][j] = __builtin_amdgcn_mfma_f32_16x16x32_bf16(x0, bfr[j][0], acc[0][j], 0, 0, 0);
        acc[0][j] = __builtin_amdgcn_mfma_f32_16x16x32_bf16(x1, bfr[j][1], acc[0][j], 0, 0, 0);
        acc[1][j] = __builtin_amdgcn_mfma_f32_16x16x32_bf16(y0, bfr[j][0], acc[1][j], 0, 0, 0);
        acc[1][j] = __builtin_amdgcn_mfma_f32_16x16x32_bf16(y1, bfr[j][1], acc[1][j], 0, 0, 0);
      }
      __builtin_amdgcn_s_setprio(0);
      BARRIER();
    }
    stageB(t + 1, 0); stageB(t + 1, 1);
    {
      short8 x0 = rdA(s, 2, 0), x1 = rdA(s, 2, 1);
      short8 y0 = rdA(s, 3, 0), y1 = rdA(s, 3, 1);
      BARRIER();
      __builtin_amdgcn_s_setprio(1);
#pragma unroll
      for (int j = 0; j < 4; ++j) {
        acc[2][j] = __builtin_amdgcn_mfma_f32_16x16x32_bf16(x0, bfr[j][0], acc[2][j], 0, 0, 0);
        acc[2][j] = __builtin_amdgcn_mfma_f32_16x16x32_bf16(x1, bfr[j][1], acc[2][j], 0, 0, 0);
        acc[3][j] = __builtin_amdgcn_mfma_f32_16x16x32_bf16(y0, bfr[j][0], acc[3][j], 0, 0, 0);
        acc[3][j] = __builtin_amdgcn_mfma_f32_16x16x32_bf16(y1, bfr[j][1], acc[3][j], 0, 0, 0);
      }
      __builtin_amdgcn_s_setprio(0);
      BARRIER();
    }
    stageB(t + 1, 2); stageB(t + 1, 3);
    {
      short8 x0 = rdA(s, 4, 0), x1 = rdA(s, 4, 1);
      short8 y0 = rdA(s, 5, 0), y1 = rdA(s, 5, 1);
      BARRIER();
      __builtin_amdgcn_s_setprio(1);
#pragma unroll
      for (int j = 0; j < 4; ++j) {
        acc[4][j] = __builtin_amdgcn_mfma_f32_16x16x32_bf16(x0, bfr[j][0], acc[4][j], 0, 0, 0);
        acc[4][j] = __builtin_amdgcn_mfma_f32_16x16x32_bf16(x1, bfr[j][1], acc[4][j], 0, 0, 0);
        acc[5][j] = __builtin_amdgcn_mfma_f32_16x16x32_bf16(y0, bfr[j][0], acc[5][j], 0, 0, 0);
        acc[5][j] = __builtin_amdgcn_mfma_f32_16x16x32_bf16(y1, bfr[j][1], acc[5][j], 0, 0, 0);
      }
      __builtin_amdgcn_s_setprio(0);
      BARRIER();
    }
    {
      short8 x0 = rdA(s, 6, 0), x1 = rdA(s, 6, 1);
      short8 y0 = rdA(s, 7, 0), y1 = rdA(s, 7, 1);
      asm volatile("s_waitcnt vmcnt(4)" ::: "memory");
      writeA(t + 1);
      asm volatile("s_waitcnt lgkmcnt(0)" ::: "memory");
      BARRIER();
      __builtin_amdgcn_s_setprio(1);
#pragma unroll
      for (int j = 0; j < 4; ++j) {
        acc[6][j] = __builtin_amdgcn_mfma_f32_16x16x32_bf16(x0, bfr[j][0], acc[6][j], 0, 0, 0);
        acc[6][j] = __builtin_amdgcn_mfma_f32_16x16x32_bf16(x1, bfr[j][1], acc[6][j], 0, 0, 0);
        acc[7][j] = __builtin_amdgcn_mfma_f32_16x16x32_bf16(y0, bfr[j][0], acc[7][j], 0, 0, 0);
        acc[7][j] = __builtin_amdgcn_mfma_f32_16x16x32_bf16(y1, bfr[j][1], acc[7][j], 0, 0, 0);
      }
      __builtin_amdgcn_s_setprio(0);
      asm volatile("s_waitcnt vmcnt(0)" ::: "memory");
      BARRIER();
    }
  }

#pragma unroll
  for (int i = 0; i < 8; ++i)
#pragma unroll
    for (int j = 0; j < 4; ++j)
#pragma unroll
      for (int r = 0; r < 4; ++r)
        epi_q(m0 + wm * 128 + i * 16 + lr4 + r, n0 + wn * 64 + j * 16 + lr,
              acc[i][j][r], outp);
}

// ---------- mega-fused kv-proj + attention + out-proj: 16 waves = 8 heads x 2 halves ----------
// grid 512 = (b, win); LDS 160KB:
//   Cy [0,32K)B  | per-head SL 16K at 32K+head*16K (Wkv dbuf -> K buf0, V^T buf1)
//   OA [32K,96K)B (overlays heads 0-3) | WP [96K,160K)B 16 x 4K slices (overlays heads 4-7)
__global__ __launch_bounds__(1024)
void kvattn(const unsigned short* __restrict__ y2,
            const unsigned short* __restrict__ Wkv_b,
            const unsigned short* __restrict__ qwin,
            const unsigned short* __restrict__ Wproj_b,
            const float* __restrict__ bproj,
            float* __restrict__ out) {
  __shared__ unsigned short lds[81920];
  const int tid = threadIdx.x;
  const int wv16 = tid >> 6;          // 0..15
  const int head = wv16 >> 1;
  const int half = wv16 & 1;
  const int lane = tid & 63;
  const int lr = lane & 15;
  const int lg = lane >> 4;
  const int r8 = lane >> 3;
  const int sl8 = lane & 7;
  const int bb = blockIdx.x >> 6;
  const int win = blockIdx.x & 63;
  const int ht = win >> 3, wt = win & 7;

  unsigned short* Cy  = lds;                         // 16384 shorts
  unsigned short* SLh = lds + 16384 + head * 8192;   // per-head 8192 shorts
  unsigned short* OA  = lds + 16384;                 // 32768 shorts
  unsigned short* WPs = lds + 49152 + wv16 * 2048;   // per-(head,half) 2048 shorts

  // ---- Cy: each wave stages 2 of the 32 (panel,rowblock) groups ----
  {
    int rb = wv16 & 7;
    int m = rb * 8 + r8;
    int mm = (m < 49) ? m : 48;
    int grow = bb * 3136 + (ht * 7 + mm / 7) * 56 + wt * 7 + (mm % 7);
    int p0 = wv16 >> 3;
#pragma unroll
    for (int pp = 0; pp < 2; ++pp) {
      int panel = p0 + pp * 2;
      GLOAD16(y2 + (size_t)grow * 256 + panel * 64 + ((sl8 ^ (m & 7)) * 8),
              &Cy[panel * 4096 + rb * 512]);
    }
  }

  // ---- per-(head,half) Wkv staging: own 32 rows of the head's 64x64 tile ----
  auto stageW = [&](int s) {  // s: h2=s>>2, kt=s&3
    int h2 = s >> 2, kt = s & 3;
#pragma unroll
    for (int c = 0; c < 4; ++c) {
      int lrow = half * 32 + c * 8 + r8;   // local tile row; lrow&7 == r8
      GLOAD16(Wkv_b + (size_t)(h2 * 512 + head * 64 + lrow) * 256 + kt * 64 + ((sl8 ^ r8) * 8),
              &SLh[(s & 1) * 4096 + (half * 32 + c * 8) * 64]);
    }
  };

  f32x4 aK[4][2], aV[4][2];
#pragma unroll
  for (int i = 0; i < 4; ++i)
#pragma unroll
    for (int j = 0; j < 2; ++j) { aK[i][j] = (f32x4){0,0,0,0}; aV[i][j] = (f32x4){0,0,0,0}; }

  stageW(0);
  asm volatile("s_waitcnt vmcnt(4)" ::: "memory");  // retire the 2 Cy loads (W0's 4 in flight)
  BARRIER();                                        // (1) Cy visible

#pragma unroll
  for (int s = 0; s < 8; ++s) {
    if (s < 7) {
      stageW(s + 1);
      asm volatile("s_waitcnt vmcnt(4)" ::: "memory");  // retire stage s
    } else {
      asm volatile("s_waitcnt vmcnt(0)" ::: "memory");
    }
    const int kt = s & 3;
    const unsigned short* Wb = &SLh[(s & 1) * 4096];
    short8 bfrg[2][2];
#pragma unroll
    for (int nf2 = 0; nf2 < 2; ++nf2)
#pragma unroll
      for (int ks = 0; ks < 2; ++ks) {
        int row = (half * 2 + nf2) * 16 + lr;   // own-half rows only
        bfrg[nf2][ks] = *(const short8*)&Wb[row * 64 + (((ks * 4 + lg) ^ (lr & 7)) * 8)];
      }
#pragma unroll
    for (int mf = 0; mf < 4; ++mf)
#pragma unroll
      for (int ks = 0; ks < 2; ++ks) {
        short8 af = *(const short8*)&Cy[kt * 4096 + (mf * 16 + lr) * 64 + (((ks * 4 + lg) ^ (lr & 7)) * 8)];
#pragma unroll
        for (int nf2 = 0; nf2 < 2; ++nf2) {
          if (s < 4)
            aK[mf][nf2] = __builtin_amdgcn_mfma_f32_16x16x32_bf16(af, bfrg[nf2][ks], aK[mf][nf2], 0, 0, 0);
          else
            aV[mf][nf2] = __builtin_amdgcn_mfma_f32_16x16x32_bf16(af, bfrg[nf2][ks], aV[mf][nf2], 0, 0, 0);
        }
      }
  }

  // ---- q fragments (own-half q rows), issued early to hide latency ----
  const unsigned short* qb = qwin + (size_t)((bb * 8 + head) * 64 + win) * 3136;
  short8 qf[2][2];
#pragma unroll
  for (int mf2 = 0; mf2 < 2; ++mf2)
#pragma unroll
    for (int ks = 0; ks < 2; ++ks)
      qf[mf2][ks] = *(const short8*)&qb[((half * 2 + mf2) * 16 + lr) * 64 + ks * 32 + lg * 8];

  BARRIER();  // (2) all waves done reading staged Wkv tiles -> safe to overwrite with K/V

  // ---- K -> buf0 [key][d own-half], V^T -> buf1 [d own-half][key] ----
#pragma unroll
  for (int mf = 0; mf < 4; ++mf)
#pragma unroll
    for (int nf2 = 0; nf2 < 2; ++nf2)
#pragma unroll
      for (int r = 0; r < 4; ++r) {
        int key = mf * 16 + lg * 4 + r;
        int d = (half * 2 + nf2) * 16 + lr;
        SLh[key * 64 + (((d >> 3) ^ (key & 7)) * 8) + (d & 7)] = f2bf(aK[mf][nf2][r]);
        SLh[4096 + d * 64 + (((key >> 3) ^ (d & 7)) * 8) + (key & 7)] = f2bf(aV[mf][nf2][r]);
      }
  asm volatile("s_waitcnt lgkmcnt(0)" ::: "memory");
  BARRIER();  // (3) K & V^T complete (cross-half reads follow)

  // ---- QK^T: own-half q rows x all 64 keys ----
  f32x4 aS[2][4];
#pragma unroll
  for (int i = 0; i < 2; ++i)
#pragma unroll
    for (int j = 0; j < 4; ++j) aS[i][j] = (f32x4){0,0,0,0};
#pragma unroll
  for (int mf2 = 0; mf2 < 2; ++mf2)
#pragma unroll
    for (int ks = 0; ks < 2; ++ks)
#pragma unroll
      for (int nf = 0; nf < 4; ++nf) {
        short8 bk = *(const short8*)&SLh[(nf * 16 + lr) * 64 + (((ks * 4 + lg) ^ (lr & 7)) * 8)];
        aS[mf2][nf] = __builtin_amdgcn_mfma_f32_16x16x32_bf16(qf[mf2][ks], bk, aS[mf2][nf], 0, 0, 0);
      }

  // ---- softmax over keys (mask >=49) ----
#pragma unroll
  for (int nf = 0; nf < 4; ++nf)
    if (nf * 16 + lr >= 49) {
#pragma unroll
      for (int mf2 = 0; mf2 < 2; ++mf2)
#pragma unroll
        for (int r = 0; r < 4; ++r) aS[mf2][nf][r] = -1e30f;
    }
  const float cexp = 0.125f * 1.4426950408889634f;
  float mx[2][4], sm[2][4];
#pragma unroll
  for (int mf2 = 0; mf2 < 2; ++mf2)
#pragma unroll
    for (int r = 0; r < 4; ++r)
      mx[mf2][r] = fmaxf(fmaxf(aS[mf2][0][r], aS[mf2][1][r]), fmaxf(aS[mf2][2][r], aS[mf2][3][r]));
#pragma unroll
  for (int m = 1; m <= 8; m <<= 1)
#pragma unroll
    for (int mf2 = 0; mf2 < 2; ++mf2)
#pragma unroll
      for (int r = 0; r < 4; ++r) mx[mf2][r] = fmaxf(mx[mf2][r], __shfl_xor(mx[mf2][r], m));
#pragma unroll
  for (int mf2 = 0; mf2 < 2; ++mf2)
#pragma unroll
    for (int nf = 0; nf < 4; ++nf)
#pragma unroll
      for (int r = 0; r < 4; ++r)
        aS[mf2][nf][r] = exp2f((aS[mf2][nf][r] - mx[mf2][r]) * cexp);
#pragma unroll
  for (int mf2 = 0; mf2 < 2; ++mf2)
#pragma unroll
    for (int r = 0; r < 4; ++r)
      sm[mf2][r] = aS[mf2][0][r] + aS[mf2][1][r] + aS[mf2][2][r] + aS[mf2][3][r];
#pragma unroll
  for (int m = 1; m <= 8; m <<= 1)
#pragma unroll
    for (int mf2 = 0; mf2 < 2; ++mf2)
#pragma unroll
      for (int r = 0; r < 4; ++r) sm[mf2][r] += __shfl_xor(sm[mf2][r], m);
#pragma unroll
  for (int mf2 = 0; mf2 < 2; ++mf2)
#pragma unroll
    for (int r = 0; r < 4; ++r) sm[mf2][r] = 1.f / sm[mf2][r];

  BARRIER();  // (4) all waves done reading K -> safe to overwrite buf0 with P

  // ---- P -> buf0 (own-half q rows) ----
#pragma unroll
  for (int mf2 = 0; mf2 < 2; ++mf2)
#pragma unroll
    for (int nf = 0; nf < 4; ++nf)
#pragma unroll
      for (int r = 0; r < 4; ++r) {
        int q = (half * 2 + mf2) * 16 + lg * 4 + r;
        int key = nf * 16 + lr;
        SLh[q * 64 + (((key >> 3) ^ (q & 7)) * 8) + (key & 7)] = f2bf(aS[mf2][nf][r] * sm[mf2][r]);
      }

  // ---- PV: own P rows x stable V^T (wave-local reads of own writes + pre-(3) V) ----
  f32x4 aO[2][4];
#pragma unroll
  for (int i = 0; i < 2; ++i)
#pragma unroll
    for (int j = 0; j < 4; ++j) aO[i][j] = (f32x4){0,0,0,0};
#pragma unroll
  for (int mf2 = 0; mf2 < 2; ++mf2)
#pragma unroll
    for (int ks = 0; ks < 2; ++ks) {
      int qrow = (half * 2 + mf2) * 16 + lr;
      short8 pf = *(const short8*)&SLh[qrow * 64 + (((ks * 4 + lg) ^ (lr & 7)) * 8)];
#pragma unroll
      for (int df = 0; df < 4; ++df) {
        short8 vf = *(const short8*)&SLh[4096 + (df * 16 + lr) * 64 + (((ks * 4 + lg) ^ (lr & 7)) * 8)];
        aO[mf2][df] = __builtin_amdgcn_mfma_f32_16x16x32_bf16(pf, vf, aO[mf2][df], 0, 0, 0);
      }
    }

  BARRIER();  // (5) all waves done PV -> SL regions reusable as OA / WP

  // ---- OA [64q][512] (own-half q rows, own head cols) + first WP tile ----
#pragma unroll
  for (int mf2 = 0; mf2 < 2; ++mf2)
#pragma unroll
    for (int df = 0; df < 4; ++df)
#pragma unroll
      for (int r = 0; r < 4; ++r) {
        int q = (half * 2 + mf2) * 16 + lg * 4 + r;
        int slot = df * 2 + (lr >> 3);
        OA[q * 512 + head * 64 + ((slot ^ (q & 7)) * 8) + (lr & 7)] = f2bf(aO[mf2][df][r]);
      }
  // WP tile kt=0: own 32 Wproj rows (head*64 + half*32 ..)
#pragma unroll
  for (int c = 0; c < 4; ++c) {
    int lrow = c * 8 + r8;  // local 0..31; lrow&7 == r8
    GLOAD16(Wproj_b + (size_t)(head * 64 + half * 32 + lrow) * 512 + ((sl8 ^ r8) * 8),
            &WPs[c * 512]);
  }
  asm volatile("s_waitcnt lgkmcnt(0) vmcnt(0)" ::: "memory");
  BARRIER();  // (6) OA + WP(0) ready

  // ---- out-proj: all 64 q rows x own 32 cols; per-wave reg-prefetch pipeline ----
  f32x4 aR[4][2];
#pragma unroll
  for (int i = 0; i < 4; ++i)
#pragma unroll
    for (int j = 0; j < 2; ++j) aR[i][j] = (f32x4){0,0,0,0};
#pragma unroll
  for (int kt = 0; kt < 8; ++kt) {
    short8 nx[4];
    if (kt < 7) {
#pragma unroll
      for (int c = 0; c < 4; ++c) {
        int lrow = c * 8 + r8;
        nx[c] = *(const short8*)&Wproj_b[(size_t)(head * 64 + half * 32 + lrow) * 512
                                         + (kt + 1) * 64 + ((sl8 ^ r8) * 8)];
      }
    }
#pragma unroll
    for (int mf = 0; mf < 4; ++mf)
#pragma unroll
      for (int ks = 0; ks < 2; ++ks) {
        short8 af = *(const short8*)&OA[(mf * 16 + lr) * 512 + kt * 64 + (((ks * 4 + lg) ^ (lr & 7)) * 8)];
#pragma unroll
        for (int nf2 = 0; nf2 < 2; ++nf2) {
          short8 bf2 = *(const short8*)&WPs[(nf2 * 16 + lr) * 64 + (((ks * 4 + lg) ^ (lr & 7)) * 8)];
          aR[mf][nf2] = __builtin_amdgcn_mfma_f32_16x16x32_bf16(af, bf2, aR[mf][nf2], 0, 0, 0);
        }
      }
    if (kt < 7) {
#pragma unroll
      for (int c = 0; c < 4; ++c)
        *(short8*)&WPs[(c * 8 + r8) * 64 + sl8 * 8] = nx[c];
    }
  }

  // ---- epilogue: +bias, f32 store (q<49), own 32 cols ----
#pragma unroll
  for (int mf = 0; mf < 4; ++mf)
#pragma unroll
    for (int nf2 = 0; nf2 < 2; ++nf2)
#pragma unroll
      for (int r = 0; r < 4; ++r) {
        int q = mf * 16 + lg * 4 + r;
        if (q < 49) {
          int gm = bb * 3136 + (ht * 7 + q / 7) * 56 + wt * 7 + (q % 7);
          int col = head * 64 + (half * 2 + nf2) * 16 + lr;
          out[(size_t)gm * 512 + col] = aR[mf][nf2][r] + bproj[col];
        }
      }
}

// ---------- launcher ----------
extern "C" void kernel_launch(void* const* d_in, const int* in_sizes, int n_in,
                              void* d_out, int out_size, void* d_ws, size_t ws_size,
                              hipStream_t stream) {
  const float* x     = (const float*)d_in[0];
  const float* y     = (const float*)d_in[1];
  const float* Wq    = (const float*)d_in[2];
  const float* Wkv   = (const float*)d_in[3];
  const float* Wproj = (const float*)d_in[4];
  const float* bproj = (const float*)d_in[5];
  const float* Wsr   = (const float*)d_in[6];
  const float* bsr   = (const float*)d_in[7];
  const float* gn    = (const float*)d_in[8];
  const float* bn    = (const float*)d_in[9];
  float* out = (float*)d_out;

  char* ws = (char*)d_ws;
  unsigned short* Wq_b    = (unsigned short*)ws; ws += 524288;
  unsigned short* Wkv_b   = (unsigned short*)ws; ws += 524288;
  unsigned short* Wproj_b = (unsigned short*)ws; ws += 524288;
  unsigned short* Wsr_b   = (unsigned short*)ws; ws += 131072;
  unsigned short* regA    = (unsigned short*)ws; ws += 12845056; // pooled bf16
  unsigned short* q_win   = (unsigned short*)ws; ws += 25690112; // q windows
  unsigned short* regC    = (unsigned short*)ws; ws += 12845056; // y2 bf16

  // pool y -> regA | weight converts
  cvt_pool<<<7104, 256, 0, stream>>>(y, regA, Wq, Wkv, Wproj, Wsr,
                                     Wq_b, Wkv_b, Wproj_b, Wsr_b);

  // q projection (fused f32->bf16 A-staging) -> window layout
  gemm256f<512, 512><<<dim3(2, 98), 512, 0, stream>>>(x, Wq_b, q_win);

  // fused conv+bias+LN+GELU -> y2
  sr_gemm<<<392, 256, 0, stream>>>(regA, Wsr_b, bsr, gn, bn, regC);

  // mega-fused kv-proj + attention + out-proj (16 waves) -> f32 d_out
  kvattn<<<512, 1024, 0, stream>>>(regC, Wkv_b, q_win, Wproj_b, bproj, out);
}